// Round 1
// baseline (862.656 us; speedup 1.0000x reference)
//
#include <hip/hip_runtime.h>
#include <math.h>

#define B_ 4
#define C_ 256
#define L_ 4096
#define E_ 256
#define NH_ 8
#define HD_ 32
#define TOPK_ 512
#define MLP_ 1024
#define EPS_ 1e-5f

// ---------------- transpose (B,256,4096) -> (B,4096,256) ----------------
__global__ __launch_bounds__(256) void k_transpose(const float* __restrict__ in, float* __restrict__ out) {
  __shared__ float tile[32][33];
  int b = blockIdx.z;
  int l0 = blockIdx.x * 32, c0 = blockIdx.y * 32;
  const float* ib = in + (long)b * C_ * L_;
  float* ob = out + (long)b * L_ * C_;
  int tx = threadIdx.x, ty = threadIdx.y;
#pragma unroll
  for (int i = ty; i < 32; i += 8) tile[i][tx] = ib[(long)(c0 + i) * L_ + l0 + tx];
  __syncthreads();
#pragma unroll
  for (int i = ty; i < 32; i += 8) ob[(long)(l0 + i) * C_ + c0 + tx] = tile[tx][i];
}

// ---------------- final: out[b][c][l] = X[b][l][c] + Y[b][l][c] ----------------
__global__ __launch_bounds__(256) void k_final(const float* __restrict__ X, const float* __restrict__ Y,
                                               float* __restrict__ out) {
  __shared__ float tile[32][33];
  int b = blockIdx.z;
  int l0 = blockIdx.x * 32, c0 = blockIdx.y * 32;
  int tx = threadIdx.x, ty = threadIdx.y;
  const float* Xb = X + (long)b * L_ * C_;
  const float* Yb = Y + (long)b * L_ * C_;
  float* ob = out + (long)b * C_ * L_;
#pragma unroll
  for (int i = ty; i < 32; i += 8) {
    long off = (long)(l0 + i) * C_ + c0 + tx;
    tile[i][tx] = Xb[off] + Yb[off];
  }
  __syncthreads();
#pragma unroll
  for (int i = ty; i < 32; i += 8) ob[(long)(c0 + i) * L_ + l0 + tx] = tile[tx][i];
}

// ---------------- gather rows: dst[b][r][:] = src[b][ind[b][r]][:] ----------------
__global__ __launch_bounds__(256) void k_gather_rows(const float* __restrict__ src, const int* __restrict__ ind,
                                                     float* __restrict__ dst, int nrows) {
  int gr = blockIdx.x * 4 + (threadIdx.x >> 6);
  int b = gr / nrows, r = gr % nrows;
  int c = (threadIdx.x & 63) * 4;
  int idx = ind[b * nrows + r];
  *(float4*)(dst + ((long)b * nrows + r) * C_ + c) = *(const float4*)(src + ((long)b * L_ + idx) * C_ + c);
}

__global__ void k_init_md(unsigned* md) { md[blockIdx.x * 256 + threadIdx.x] = 0x7f800000u; }

// ---------------- min-L1 distance ----------------
// grid (L_/128, B_, 8 query-slices), block 256.
// Thread owns 2 kv tokens x 64 channels in registers; 32 queries staged in LDS.
__global__ __launch_bounds__(256) void k_dist(const float* __restrict__ Kt, const float* __restrict__ Qs,
                                              unsigned* __restrict__ mdbits) {
  __shared__ float Ql[32][256];  // 32KB
  const int b = blockIdx.y, tb = blockIdx.x, qz = blockIdx.z;
  const int tid = threadIdx.x;
  const int cg = tid & 3, slot = tid >> 2;
  const int T0 = tb * 128 + slot;
  const float* k0p = Kt + ((long)b * L_ + T0) * C_ + cg * 64;
  const float* k1p = k0p + 64 * C_;
  float4 K0[16], K1[16];
#pragma unroll
  for (int j = 0; j < 16; j++) {
    K0[j] = ((const float4*)k0p)[j];
    K1[j] = ((const float4*)k1p)[j];
  }
  float m0 = INFINITY, m1 = INFINITY;
  for (int qc = 0; qc < 2; qc++) {
    __syncthreads();
    const float* qsrc = Qs + ((long)b * TOPK_ + qz * 64 + qc * 32) * C_;
#pragma unroll
    for (int v = 0; v < 8; v++) {
      int f = (tid + v * 256) * 4;
      int r = f >> 8, c = f & 255;
      *(float4*)&Ql[r][c] = *(const float4*)(qsrc + (long)r * C_ + c);
    }
    __syncthreads();
    for (int q = 0; q < 32; q++) {
      const float4* qr = (const float4*)&Ql[q][cg * 64];
      float a0 = 0, a1 = 0, a2 = 0, a3 = 0, b0 = 0, b1 = 0, b2 = 0, b3 = 0;
#pragma unroll
      for (int j = 0; j < 16; j++) {
        float4 qv = qr[j];
        a0 += fabsf(K0[j].x - qv.x); a1 += fabsf(K0[j].y - qv.y);
        a2 += fabsf(K0[j].z - qv.z); a3 += fabsf(K0[j].w - qv.w);
        b0 += fabsf(K1[j].x - qv.x); b1 += fabsf(K1[j].y - qv.y);
        b2 += fabsf(K1[j].z - qv.z); b3 += fabsf(K1[j].w - qv.w);
      }
      float s0 = (a0 + a1) + (a2 + a3);
      float s1 = (b0 + b1) + (b2 + b3);
      s0 += __shfl_xor(s0, 1); s0 += __shfl_xor(s0, 2);
      s1 += __shfl_xor(s1, 1); s1 += __shfl_xor(s1, 2);
      m0 = fminf(m0, s0);
      m1 = fminf(m1, s1);
    }
  }
  if (cg == 0) {
    atomicMin(&mdbits[b * L_ + T0], __float_as_uint(m0));
    atomicMin(&mdbits[b * L_ + T0 + 64], __float_as_uint(m1));
  }
}

// ---------------- bitonic sort 4096 keys per batch; keep 512 smallest ----------------
__global__ __launch_bounds__(1024) void k_sort(const unsigned* __restrict__ mdb, unsigned* __restrict__ idxsel) {
  __shared__ unsigned long long s[4096];
  const int b = blockIdx.x, tid = threadIdx.x;
  for (int i = tid; i < 4096; i += 1024)
    s[i] = (((unsigned long long)mdb[b * L_ + i]) << 32) | (unsigned)i;
  __syncthreads();
  for (int k = 2; k <= 4096; k <<= 1)
    for (int j = k >> 1; j > 0; j >>= 1) {
      for (int i = tid; i < 4096; i += 1024) {
        int ixj = i ^ j;
        if (ixj > i) {
          bool up = ((i & k) == 0);
          unsigned long long a = s[i], c = s[ixj];
          if ((a > c) == up) { s[i] = c; s[ixj] = a; }
        }
      }
      __syncthreads();
    }
  for (int i = tid; i < TOPK_; i += 1024) idxsel[b * TOPK_ + i] = (unsigned)(s[i] & 0xFFFFFFFFu);
}

// ---------------- generic fp32 tiled GEMM: C[m,n] = f(sum_k A[m,k]*B[n,k] + bias[n]) ----------------
// MODE 0: +bias (bias may be null). MODE 2: bias + batchnorm + relu. MODE 3: bias + batchnorm.
template <int BM, int BN, int BK, int TM, int TN, int MODE>
__global__ __launch_bounds__((BM / TM) * (BN / TN)) void k_gemm(
    const float* __restrict__ A, const float* __restrict__ Bm, float* __restrict__ C, int M, int N, int K, int lda,
    int ldb, int ldc, const float* __restrict__ bias, const float* __restrict__ g, const float* __restrict__ be,
    const float* __restrict__ mu, const float* __restrict__ va) {
  constexpr int NTH = (BM / TM) * (BN / TN);
  constexpr int XT = BN / TN;
  __shared__ float As[BK][BM];
  __shared__ float Bs[BK][BN];
  const int tid = threadIdx.x;
  const int tx = tid % XT, ty = tid / XT;
  const float* Ab = A + (long)blockIdx.y * BM * lda;
  const float* Bb = Bm + (long)blockIdx.x * BN * ldb;
  float acc[TM][TN] = {};
  for (int k0 = 0; k0 < K; k0 += BK) {
#pragma unroll
    for (int v = 0; v < BM * BK / 4 / NTH; v++) {
      int f = (tid + v * NTH) * 4;
      int r = f / BK, c = f % BK;
      float4 x = *(const float4*)(Ab + (long)r * lda + k0 + c);
      As[c + 0][r] = x.x; As[c + 1][r] = x.y; As[c + 2][r] = x.z; As[c + 3][r] = x.w;
    }
#pragma unroll
    for (int v = 0; v < BN * BK / 4 / NTH; v++) {
      int f = (tid + v * NTH) * 4;
      int r = f / BK, c = f % BK;
      float4 x = *(const float4*)(Bb + (long)r * ldb + k0 + c);
      Bs[c + 0][r] = x.x; Bs[c + 1][r] = x.y; Bs[c + 2][r] = x.z; Bs[c + 3][r] = x.w;
    }
    __syncthreads();
#pragma unroll
    for (int kk = 0; kk < BK; kk++) {
      float a[TM], bv[TN];
#pragma unroll
      for (int i = 0; i < TM; i += 4) *(float4*)&a[i] = *(const float4*)&As[kk][ty * TM + i];
#pragma unroll
      for (int j = 0; j < TN; j += 4) *(float4*)&bv[j] = *(const float4*)&Bs[kk][tx * TN + j];
#pragma unroll
      for (int i = 0; i < TM; i++)
#pragma unroll
        for (int j = 0; j < TN; j++) acc[i][j] += a[i] * bv[j];
    }
    __syncthreads();
  }
  const int m0 = blockIdx.y * BM + ty * TM;
  const int n0 = blockIdx.x * BN + tx * TN;
#pragma unroll
  for (int i = 0; i < TM; i++) {
    float o[TN];
#pragma unroll
    for (int j = 0; j < TN; j++) {
      float v = acc[i][j];
      int n = n0 + j;
      if (MODE == 0) {
        if (bias) v += bias[n];
      } else {
        v += bias[n];
        float inv = g[n] / sqrtf(va[n] + EPS_);
        v = v * inv + (be[n] - mu[n] * inv);
        if (MODE == 2) v = fmaxf(v, 0.f);
      }
      o[j] = v;
    }
#pragma unroll
    for (int j = 0; j < TN; j += 4) *(float4*)(C + (long)(m0 + i) * ldc + n0 + j) = *(float4*)&o[j];
  }
}

// ---------------- fused flash attention over the 512 selected tokens ----------------
// grid (L_/64, NH_, B_), block 256. Per block: 64 q-rows, one head, streaming 8 chunks of 64 tokens.
__global__ __launch_bounds__(256) void k_attn(const float* __restrict__ qp, const float* __restrict__ kv,
                                              float* __restrict__ ctxo) {
  __shared__ float Qs[32][64];   // [k][m]
  __shared__ float Ks[32][64];   // [k][t]
  __shared__ float Vs[64][32];   // [t][d]
  __shared__ float PT[64][68];   // [t][m], padded
  const int tid = threadIdx.x;
  const int b = blockIdx.z, h = blockIdx.y, qt = blockIdx.x;
  const float scale = 0.17677669529663687f;  // 1/sqrt(32)
  {
    int r = tid >> 2, c0 = (tid & 3) * 8;
    const float* src = qp + ((long)(b * L_ + qt * 64 + r)) * E_ + h * HD_ + c0;
    float4 x0 = *(const float4*)src;
    float4 x1 = *(const float4*)(src + 4);
    Qs[c0 + 0][r] = x0.x * scale; Qs[c0 + 1][r] = x0.y * scale;
    Qs[c0 + 2][r] = x0.z * scale; Qs[c0 + 3][r] = x0.w * scale;
    Qs[c0 + 4][r] = x1.x * scale; Qs[c0 + 5][r] = x1.y * scale;
    Qs[c0 + 6][r] = x1.z * scale; Qs[c0 + 7][r] = x1.w * scale;
  }
  const int tx = tid & 15, ty = tid >> 4;
  float mrun[4], lrun[4], cacc[4][2];
#pragma unroll
  for (int i = 0; i < 4; i++) { mrun[i] = -INFINITY; lrun[i] = 0.f; cacc[i][0] = 0.f; cacc[i][1] = 0.f; }
  for (int t0 = 0; t0 < TOPK_; t0 += 64) {
    __syncthreads();
    {
      int t = tid >> 2, c0 = (tid & 3) * 8;
      const float* kp = kv + ((long)(b * TOPK_ + t0 + t)) * 512 + h * HD_ + c0;
      float4 a0 = *(const float4*)kp;
      float4 a1 = *(const float4*)(kp + 4);
      Ks[c0 + 0][t] = a0.x; Ks[c0 + 1][t] = a0.y; Ks[c0 + 2][t] = a0.z; Ks[c0 + 3][t] = a0.w;
      Ks[c0 + 4][t] = a1.x; Ks[c0 + 5][t] = a1.y; Ks[c0 + 6][t] = a1.z; Ks[c0 + 7][t] = a1.w;
      const float* vp = kp + 256;
      *(float4*)&Vs[t][c0] = *(const float4*)vp;
      *(float4*)&Vs[t][c0 + 4] = *(const float4*)(vp + 4);
    }
    __syncthreads();
    float s[4][4] = {};
#pragma unroll
    for (int kk = 0; kk < 32; kk++) {
      float4 aq = *(const float4*)&Qs[kk][ty * 4];
      float4 bk = *(const float4*)&Ks[kk][tx * 4];
      s[0][0] += aq.x * bk.x; s[0][1] += aq.x * bk.y; s[0][2] += aq.x * bk.z; s[0][3] += aq.x * bk.w;
      s[1][0] += aq.y * bk.x; s[1][1] += aq.y * bk.y; s[1][2] += aq.y * bk.z; s[1][3] += aq.y * bk.w;
      s[2][0] += aq.z * bk.x; s[2][1] += aq.z * bk.y; s[2][2] += aq.z * bk.z; s[2][3] += aq.z * bk.w;
      s[3][0] += aq.w * bk.x; s[3][1] += aq.w * bk.y; s[3][2] += aq.w * bk.z; s[3][3] += aq.w * bk.w;
    }
#pragma unroll
    for (int i = 0; i < 4; i++) {
      float mx = fmaxf(fmaxf(s[i][0], s[i][1]), fmaxf(s[i][2], s[i][3]));
      mx = fmaxf(mx, __shfl_xor(mx, 1));
      mx = fmaxf(mx, __shfl_xor(mx, 2));
      mx = fmaxf(mx, __shfl_xor(mx, 4));
      mx = fmaxf(mx, __shfl_xor(mx, 8));
      float mnew = fmaxf(mrun[i], mx);
      float f = expf(mrun[i] - mnew);
      mrun[i] = mnew;
      float ss = 0.f;
#pragma unroll
      for (int j = 0; j < 4; j++) {
        float p = expf(s[i][j] - mnew);
        s[i][j] = p;
        ss += p;
      }
      ss += __shfl_xor(ss, 1); ss += __shfl_xor(ss, 2);
      ss += __shfl_xor(ss, 4); ss += __shfl_xor(ss, 8);
      lrun[i] = lrun[i] * f + ss;
      cacc[i][0] *= f; cacc[i][1] *= f;
    }
#pragma unroll
    for (int j = 0; j < 4; j++) {
      float4 col;
      col.x = s[0][j]; col.y = s[1][j]; col.z = s[2][j]; col.w = s[3][j];
      *(float4*)&PT[tx * 4 + j][ty * 4] = col;
    }
    __syncthreads();
#pragma unroll
    for (int t = 0; t < 64; t++) {
      float4 pm = *(const float4*)&PT[t][ty * 4];
      float2 vv = *(const float2*)&Vs[t][tx * 2];
      cacc[0][0] += pm.x * vv.x; cacc[0][1] += pm.x * vv.y;
      cacc[1][0] += pm.y * vv.x; cacc[1][1] += pm.y * vv.y;
      cacc[2][0] += pm.z * vv.x; cacc[2][1] += pm.z * vv.y;
      cacc[3][0] += pm.w * vv.x; cacc[3][1] += pm.w * vv.y;
    }
  }
#pragma unroll
  for (int i = 0; i < 4; i++) {
    float inv = 1.f / lrun[i];
    float2 o;
    o.x = cacc[i][0] * inv;
    o.y = cacc[i][1] * inv;
    *(float2*)(ctxo + ((long)(b * L_ + qt * 64 + ty * 4 + i)) * E_ + h * HD_ + tx * 2) = o;
  }
}

extern "C" void kernel_launch(void* const* d_in, const int* in_sizes, int n_in, void* d_out, int out_size, void* d_ws,
                              size_t ws_size, hipStream_t stream) {
  (void)in_sizes; (void)n_in; (void)out_size; (void)ws_size;
  const float* qs_in = (const float*)d_in[0];
  const float* ctx_in = (const float*)d_in[1];
  const int* rind = (const int*)d_in[2];
  const float* ipw = (const float*)d_in[3];
  const float* ipb = (const float*)d_in[4];
  const float* opw = (const float*)d_in[5];
  const float* opb = (const float*)d_in[6];
  const float* c1w = (const float*)d_in[7];
  const float* c1b = (const float*)d_in[8];
  const float* g1 = (const float*)d_in[9];
  const float* b1 = (const float*)d_in[10];
  const float* mu1 = (const float*)d_in[11];
  const float* v1 = (const float*)d_in[12];
  const float* c2w = (const float*)d_in[13];
  const float* c2b = (const float*)d_in[14];
  const float* g2 = (const float*)d_in[15];
  const float* b2 = (const float*)d_in[16];
  const float* mu2 = (const float*)d_in[17];
  const float* v2 = (const float*)d_in[18];
  float* out = (float*)d_out;
  float* ws = (float*)d_ws;

  // workspace layout (float offsets); total 75 MB
  float* Kt = ws;                       // 16MB region A; later reused as qproj
  float* Qt = ws + 4194304;             // 16MB region Bf
  float* H = ws;                        // 32MB (A+Bf) for MLP hidden, used after attention
  float* Qsbuf = ws + 8388608;          // 2MB
  unsigned* md = (unsigned*)(ws + 8912896);      // 64KB
  unsigned* idxsel = (unsigned*)(ws + 9175040);  // 8KB
  float* ksel = ws + 9437184;           // 2MB
  float* kv = ws + 10485760;            // 4MB
  float* ctxb = ws + 11534336;          // 16MB region E; later reused as Y
  float* X = ws + 15728640;             // 16MB region F
  float* qproj = Kt;
  float* Y = ctxb;

  dim3 tb(32, 8);
  k_transpose<<<dim3(128, 8, 4), tb, 0, stream>>>(ctx_in, Kt);
  k_transpose<<<dim3(128, 8, 4), tb, 0, stream>>>(qs_in, Qt);
  k_init_md<<<64, 256, 0, stream>>>(md);
  k_gather_rows<<<512, 256, 0, stream>>>(Qt, rind, Qsbuf, TOPK_);
  k_dist<<<dim3(32, 4, 8), 256, 0, stream>>>(Kt, Qsbuf, md);
  k_sort<<<4, 1024, 0, stream>>>(md, idxsel);
  k_gather_rows<<<512, 256, 0, stream>>>(Kt, (const int*)idxsel, ksel, TOPK_);
  // q projection: (16384x256) @ wq^T + bq  -> qproj (overwrites Kt region)
  k_gemm<128, 64, 16, 8, 4, 0><<<dim3(4, 128), 256, 0, stream>>>(Qt, ipw, qproj, 16384, 256, 256, 256, 256, 256, ipb,
                                                                 nullptr, nullptr, nullptr, nullptr);
  // k/v projection fused: (2048x256) @ [wk;wv]^T -> kv (2048x512)
  k_gemm<128, 64, 16, 8, 4, 0><<<dim3(8, 16), 256, 0, stream>>>(ksel, ipw + 65536, kv, 2048, 512, 256, 256, 256, 512,
                                                                ipb + 256, nullptr, nullptr, nullptr, nullptr);
  // fused attention -> ctxb (B,L,E)
  k_attn<<<dim3(64, NH_, B_), 256, 0, stream>>>(qproj, kv, ctxb);
  // out projection -> X (B,L,E)
  k_gemm<128, 64, 16, 8, 4, 0><<<dim3(4, 128), 256, 0, stream>>>(ctxb, opw, X, 16384, 256, 256, 256, 256, 256, opb,
                                                                 nullptr, nullptr, nullptr, nullptr);
  // MLP (conv1x1 -> bn -> relu -> conv1x1 -> bn), two halves to fit H in 32MB
  for (int half = 0; half < 2; half++) {
    const float* Xh = X + (long)half * 8192 * 256;
    float* Yh = Y + (long)half * 8192 * 256;
    k_gemm<128, 64, 16, 8, 4, 2><<<dim3(16, 64), 256, 0, stream>>>(Xh, c1w, H, 8192, 1024, 256, 256, 256, 1024, c1b,
                                                                   g1, b1, mu1, v1);
    k_gemm<64, 64, 32, 4, 4, 3><<<dim3(4, 128), 256, 0, stream>>>(H, c2w, Yh, 8192, 256, 1024, 1024, 1024, 256, c2b,
                                                                  g2, b2, mu2, v2);
  }
  // residual add + transpose to (B,C,H,W)
  k_final<<<dim3(128, 8, 4), tb, 0, stream>>>(X, Y, out);
}

// Round 2
// 513.318 us; speedup vs baseline: 1.6805x; 1.6805x over previous
//
#include <hip/hip_runtime.h>
#include <math.h>

#define B_ 4
#define C_ 256
#define L_ 4096
#define E_ 256
#define NH_ 8
#define HD_ 32
#define TOPK_ 512
#define MLP_ 1024
#define EPS_ 1e-5f

typedef __attribute__((ext_vector_type(4))) float f32x4;
typedef __attribute__((ext_vector_type(8))) short short8;
typedef __attribute__((ext_vector_type(2))) unsigned int u32x2;
typedef __attribute__((ext_vector_type(4))) unsigned int u32x4;

__device__ __forceinline__ unsigned short f2bf(float x) {
  unsigned u = __float_as_uint(x);
  return (unsigned short)((u + 0x7FFFu + ((u >> 16) & 1)) >> 16);
}
__device__ __forceinline__ float bf2f(unsigned short h) { return __uint_as_float((unsigned)h << 16); }

// ---------------- transpose (B,256,4096) -> (B,4096,256) ----------------
__global__ __launch_bounds__(256) void k_transpose(const float* __restrict__ in, float* __restrict__ out) {
  __shared__ float tile[32][33];
  int b = blockIdx.z;
  int l0 = blockIdx.x * 32, c0 = blockIdx.y * 32;
  const float* ib = in + (long)b * C_ * L_;
  float* ob = out + (long)b * L_ * C_;
  int tx = threadIdx.x, ty = threadIdx.y;
#pragma unroll
  for (int i = ty; i < 32; i += 8) tile[i][tx] = ib[(long)(c0 + i) * L_ + l0 + tx];
  __syncthreads();
#pragma unroll
  for (int i = ty; i < 32; i += 8) ob[(long)(l0 + i) * C_ + c0 + tx] = tile[tx][i];
}

// ---------------- final: out[b][c][l] = X[b][l][c] + Y[b][l][c] ----------------
__global__ __launch_bounds__(256) void k_final(const float* __restrict__ X, const float* __restrict__ Y,
                                               float* __restrict__ out) {
  __shared__ float tile[32][33];
  int b = blockIdx.z;
  int l0 = blockIdx.x * 32, c0 = blockIdx.y * 32;
  int tx = threadIdx.x, ty = threadIdx.y;
  const float* Xb = X + (long)b * L_ * C_;
  const float* Yb = Y + (long)b * L_ * C_;
  float* ob = out + (long)b * C_ * L_;
#pragma unroll
  for (int i = ty; i < 32; i += 8) {
    long off = (long)(l0 + i) * C_ + c0 + tx;
    tile[i][tx] = Xb[off] + Yb[off];
  }
  __syncthreads();
#pragma unroll
  for (int i = ty; i < 32; i += 8) ob[(long)(c0 + i) * L_ + l0 + tx] = tile[tx][i];
}

// ---------------- gather rows ----------------
__global__ __launch_bounds__(256) void k_gather_rows(const float* __restrict__ src, const int* __restrict__ ind,
                                                     float* __restrict__ dst, int nrows) {
  int gr = blockIdx.x * 4 + (threadIdx.x >> 6);
  int b = gr / nrows, r = gr % nrows;
  int c = (threadIdx.x & 63) * 4;
  int idx = ind[b * nrows + r];
  *(float4*)(dst + ((long)b * nrows + r) * C_ + c) = *(const float4*)(src + ((long)b * L_ + idx) * C_ + c);
}

__global__ void k_init_md(unsigned* md) { md[blockIdx.x * 256 + threadIdx.x] = 0x7f800000u; }

// ---------------- min-L1 distance ----------------
__global__ __launch_bounds__(256) void k_dist(const float* __restrict__ Kt, const float* __restrict__ Qs,
                                              unsigned* __restrict__ mdbits) {
  __shared__ float Ql[32][256];
  const int b = blockIdx.y, tb = blockIdx.x, qz = blockIdx.z;
  const int tid = threadIdx.x;
  const int cg = tid & 3, slot = tid >> 2;
  const int T0 = tb * 128 + slot;
  const float* k0p = Kt + ((long)b * L_ + T0) * C_ + cg * 64;
  const float* k1p = k0p + 64 * C_;
  float4 K0[16], K1[16];
#pragma unroll
  for (int j = 0; j < 16; j++) {
    K0[j] = ((const float4*)k0p)[j];
    K1[j] = ((const float4*)k1p)[j];
  }
  float m0 = INFINITY, m1 = INFINITY;
  for (int qc = 0; qc < 2; qc++) {
    __syncthreads();
    const float* qsrc = Qs + ((long)b * TOPK_ + qz * 64 + qc * 32) * C_;
#pragma unroll
    for (int v = 0; v < 8; v++) {
      int f = (tid + v * 256) * 4;
      int r = f >> 8, c = f & 255;
      *(float4*)&Ql[r][c] = *(const float4*)(qsrc + (long)r * C_ + c);
    }
    __syncthreads();
    for (int q = 0; q < 32; q++) {
      const float4* qr = (const float4*)&Ql[q][cg * 64];
      float a0 = 0, a1 = 0, a2 = 0, a3 = 0, b0 = 0, b1 = 0, b2 = 0, b3 = 0;
#pragma unroll
      for (int j = 0; j < 16; j++) {
        float4 qv = qr[j];
        a0 += fabsf(K0[j].x - qv.x); a1 += fabsf(K0[j].y - qv.y);
        a2 += fabsf(K0[j].z - qv.z); a3 += fabsf(K0[j].w - qv.w);
        b0 += fabsf(K1[j].x - qv.x); b1 += fabsf(K1[j].y - qv.y);
        b2 += fabsf(K1[j].z - qv.z); b3 += fabsf(K1[j].w - qv.w);
      }
      float s0 = (a0 + a1) + (a2 + a3);
      float s1 = (b0 + b1) + (b2 + b3);
      s0 += __shfl_xor(s0, 1); s0 += __shfl_xor(s0, 2);
      s1 += __shfl_xor(s1, 1); s1 += __shfl_xor(s1, 2);
      m0 = fminf(m0, s0);
      m1 = fminf(m1, s1);
    }
  }
  if (cg == 0) {
    atomicMin(&mdbits[b * L_ + T0], __float_as_uint(m0));
    atomicMin(&mdbits[b * L_ + T0 + 64], __float_as_uint(m1));
  }
}

// ---------------- bitonic sort 4096 keys per batch; keep 512 smallest ----------------
__global__ __launch_bounds__(1024) void k_sort(const unsigned* __restrict__ mdb, unsigned* __restrict__ idxsel) {
  __shared__ unsigned long long s[4096];
  const int b = blockIdx.x, tid = threadIdx.x;
  for (int i = tid; i < 4096; i += 1024)
    s[i] = (((unsigned long long)mdb[b * L_ + i]) << 32) | (unsigned)i;
  __syncthreads();
  for (int k = 2; k <= 4096; k <<= 1)
    for (int j = k >> 1; j > 0; j >>= 1) {
      for (int i = tid; i < 4096; i += 1024) {
        int ixj = i ^ j;
        if (ixj > i) {
          bool up = ((i & k) == 0);
          unsigned long long a = s[i], c = s[ixj];
          if ((a > c) == up) { s[i] = c; s[ixj] = a; }
        }
      }
      __syncthreads();
    }
  for (int i = tid; i < TOPK_; i += 1024) idxsel[b * TOPK_ + i] = (unsigned)(s[i] & 0xFFFFFFFFu);
}

// ---------------- weight fp32 -> split-bf16 "duo" layout ----------------
// D[n][kb*64 + (k&31)] = hi, D[n][kb*64 + 32 + (k&31)] = lo  (kb = k/32)
__global__ __launch_bounds__(256) void k_w2duo(const float* __restrict__ W, unsigned short* __restrict__ D,
                                               int total, int K) {
  int i = (blockIdx.x * 256 + threadIdx.x) * 4;
  if (i >= total) return;
  int n = i / K, k = i % K;
  float4 x = *(const float4*)(W + i);
  unsigned short h0 = f2bf(x.x), h1 = f2bf(x.y), h2 = f2bf(x.z), h3 = f2bf(x.w);
  unsigned short l0 = f2bf(x.x - bf2f(h0)), l1 = f2bf(x.y - bf2f(h1));
  unsigned short l2 = f2bf(x.z - bf2f(h2)), l3 = f2bf(x.w - bf2f(h3));
  u32x2 hv, lv;
  hv.x = (unsigned)h0 | ((unsigned)h1 << 16); hv.y = (unsigned)h2 | ((unsigned)h3 << 16);
  lv.x = (unsigned)l0 | ((unsigned)l1 << 16); lv.y = (unsigned)l2 | ((unsigned)l3 << 16);
  unsigned short* dst = D + (long)n * 2 * K + (k >> 5) * 64 + (k & 31);
  *(u32x2*)dst = hv;
  *(u32x2*)(dst + 32) = lv;
}

// ---------------- split-bf16 MFMA GEMM: C[m,n] = epilogue(sum_k A[m,k]*B[n,k] + bias[n]) ----------------
// A fp32 (split in-kernel), B pre-split duo. BM=128 fixed, BN in {64,128}.
// MODE 0: (v+bias)*cscale -> bf16 Cb.  MODE 1: kv dual-output (n<256 -> Cb row-major; n>=256 -> Caux transposed [b][d][t]).
// MODE 2: v+bias -> fp32 Cf.  MODE 3: bias+bn+relu -> Cf.  MODE 4: bias+bn -> Cf.
template <int BN, int MODE>
__global__ __launch_bounds__(256) void k_gemm_mfma(
    const float* __restrict__ A, const unsigned short* __restrict__ Bduo, float* __restrict__ Cf,
    unsigned short* __restrict__ Cb, unsigned short* __restrict__ Caux, int K, int N, float cscale,
    const float* __restrict__ bias, const float* __restrict__ g, const float* __restrict__ be,
    const float* __restrict__ mu, const float* __restrict__ va) {
  constexpr int NWN = (BN == 128) ? 2 : 1;
  constexpr int NWM = 4 / NWN;
  constexpr int WR = 128 / NWM;  // rows per wave
  constexpr int MG = WR / 16;
  constexpr int NG = 4;  // 64 cols per wave
  __shared__ __align__(16) unsigned short As[128 * 64];
  __shared__ __align__(16) unsigned short Bs[BN * 64];
  const int tid = threadIdx.x;
  const int wid = tid >> 6, lane = tid & 63, lr = lane & 15, lg = lane >> 4;
  const int wm = wid / NWN, wn = wid % NWN;
  const int row0 = wm * WR, col0 = wn * 64;
  char* AsB = (char*)As;
  char* BsB = (char*)Bs;
  f32x4 acc[MG][NG];
#pragma unroll
  for (int m = 0; m < MG; m++)
#pragma unroll
    for (int n = 0; n < NG; n++) acc[m][n] = (f32x4){0.f, 0.f, 0.f, 0.f};

  const int ar = tid >> 1, ah = tid & 1;
  const float* aptr = A + (long)(blockIdx.y * 128 + ar) * K + ah * 16;

  for (int kb = 0; kb < K; kb += 32) {
    if (kb) __syncthreads();
    // ---- stage A: fp32 -> hi chunks 0-3, lo chunks 4-7 (XOR swizzled) ----
    {
      const float* p = aptr + kb;
#pragma unroll
      for (int i = 0; i < 4; i++) {
        float4 x = *(const float4*)(p + i * 4);
        unsigned short h0 = f2bf(x.x), h1 = f2bf(x.y), h2 = f2bf(x.z), h3 = f2bf(x.w);
        unsigned short q0 = f2bf(x.x - bf2f(h0)), q1 = f2bf(x.y - bf2f(h1));
        unsigned short q2 = f2bf(x.z - bf2f(h2)), q3 = f2bf(x.w - bf2f(h3));
        u32x2 hv, lv;
        hv.x = (unsigned)h0 | ((unsigned)h1 << 16); hv.y = (unsigned)h2 | ((unsigned)h3 << 16);
        lv.x = (unsigned)q0 | ((unsigned)q1 << 16); lv.y = (unsigned)q2 | ((unsigned)q3 << 16);
        int c = ah * 2 + (i >> 1), sub = (i & 1) * 8;
        *(u32x2*)(AsB + ar * 128 + (((c) ^ (ar & 7)) << 4) + sub) = hv;
        *(u32x2*)(AsB + ar * 128 + (((c + 4) ^ (ar & 7)) << 4) + sub) = lv;
      }
    }
    // ---- stage B duo (already bf16: hi 32 then lo 32 per k-block) ----
    if (BN == 128) {
      int r = tid >> 1, h = tid & 1;
      const unsigned short* p = Bduo + (long)(blockIdx.x * 128 + r) * (2 * K) + kb * 2 + h * 32;
#pragma unroll
      for (int j = 0; j < 4; j++) {
        u32x4 w = *(const u32x4*)(p + j * 8);
        int c = h * 4 + j;
        *(u32x4*)(BsB + r * 128 + ((c ^ (r & 7)) << 4)) = w;
      }
    } else {
      int r = tid >> 2, qp = tid & 3;
      const unsigned short* p = Bduo + (long)(blockIdx.x * 64 + r) * (2 * K) + kb * 2 + qp * 16;
#pragma unroll
      for (int j = 0; j < 2; j++) {
        u32x4 w = *(const u32x4*)(p + j * 8);
        int c = qp * 2 + j;
        *(u32x4*)(BsB + r * 128 + ((c ^ (r & 7)) << 4)) = w;
      }
    }
    __syncthreads();
    short8 a0[MG], a1[MG], b0[NG], b1[NG];
#pragma unroll
    for (int m = 0; m < MG; m++) {
      int rr = row0 + m * 16 + lr;
      a0[m] = *(const short8*)(AsB + rr * 128 + (((0 + lg) ^ (rr & 7)) << 4));
      a1[m] = *(const short8*)(AsB + rr * 128 + (((4 + lg) ^ (rr & 7)) << 4));
    }
#pragma unroll
    for (int n = 0; n < NG; n++) {
      int rr = col0 + n * 16 + lr;
      b0[n] = *(const short8*)(BsB + rr * 128 + (((0 + lg) ^ (rr & 7)) << 4));
      b1[n] = *(const short8*)(BsB + rr * 128 + (((4 + lg) ^ (rr & 7)) << 4));
    }
#pragma unroll
    for (int m = 0; m < MG; m++)
#pragma unroll
      for (int n = 0; n < NG; n++)
        acc[m][n] = __builtin_amdgcn_mfma_f32_16x16x32_bf16(a0[m], b0[n], acc[m][n], 0, 0, 0);
#pragma unroll
    for (int m = 0; m < MG; m++)
#pragma unroll
      for (int n = 0; n < NG; n++)
        acc[m][n] = __builtin_amdgcn_mfma_f32_16x16x32_bf16(a1[m], b0[n], acc[m][n], 0, 0, 0);
#pragma unroll
    for (int m = 0; m < MG; m++)
#pragma unroll
      for (int n = 0; n < NG; n++)
        acc[m][n] = __builtin_amdgcn_mfma_f32_16x16x32_bf16(a0[m], b1[n], acc[m][n], 0, 0, 0);
  }
  // ---- epilogue ----
  const int mbase = blockIdx.y * 128 + row0 + lg * 4;
  const int nbase = blockIdx.x * BN + col0;
#pragma unroll
  for (int n = 0; n < NG; n++) {
    int nn = nbase + n * 16 + lr;
    float bb = bias[nn];
    float inv = 0.f, sh = 0.f;
    if (MODE == 3 || MODE == 4) {
      inv = g[nn] / sqrtf(va[nn] + EPS_);
      sh = be[nn] - mu[nn] * inv;
    }
#pragma unroll
    for (int m = 0; m < MG; m++) {
#pragma unroll
      for (int r = 0; r < 4; r++) {
        int mm = mbase + m * 16 + r;
        float v = acc[m][n][r] + bb;
        if (MODE == 0) {
          Cb[(long)mm * N + nn] = f2bf(v * cscale);
        } else if (MODE == 1) {
          if (nn < 256) {
            Cb[(long)mm * 256 + nn] = f2bf(v);
          } else {
            int bi = mm >> 9, t = mm & 511;
            Caux[((long)bi * 256 + (nn - 256)) * 512 + t] = f2bf(v);
          }
        } else if (MODE == 2) {
          Cf[(long)mm * N + nn] = v;
        } else {
          v = v * inv + sh;
          if (MODE == 3) v = fmaxf(v, 0.f);
          Cf[(long)mm * N + nn] = v;
        }
      }
    }
  }
}

// ---------------- MFMA flash attention over 512 selected tokens ----------------
// grid (64, NH, B), 256 thr = 4 waves; wave owns 16 q-rows, streams 8 chunks of 64 tokens.
// Scores tiny (|s|<~1) -> skip online max, P = exp(s) directly.
__global__ __launch_bounds__(256) void k_attn_mfma(const unsigned short* __restrict__ qbf,
                                                   const unsigned short* __restrict__ kvk,
                                                   const unsigned short* __restrict__ vt,
                                                   float* __restrict__ ctx) {
  __shared__ __align__(16) unsigned short PT[4 * 1024];
  const int tid = threadIdx.x, wid = tid >> 6, lane = tid & 63, lr = lane & 15, lg = lane >> 4;
  const int b = blockIdx.z, h = blockIdx.y;
  const int q0 = blockIdx.x * 64 + wid * 16;
  char* pt = (char*)(PT + wid * 1024);
  short8 qf = *(const short8*)(qbf + ((long)(b * L_ + q0 + lr)) * E_ + h * HD_ + lg * 8);
  f32x4 o0 = (f32x4){0.f, 0.f, 0.f, 0.f}, o1 = (f32x4){0.f, 0.f, 0.f, 0.f};
  float lsum = 0.f;
  for (int t0 = 0; t0 < TOPK_; t0 += 64) {
    f32x4 sc[4];
#pragma unroll
    for (int f = 0; f < 4; f++) {
      short8 kf = *(const short8*)(kvk + ((long)(b * TOPK_ + t0 + f * 16 + lr)) * E_ + h * HD_ + lg * 8);
      f32x4 z = (f32x4){0.f, 0.f, 0.f, 0.f};
      sc[f] = __builtin_amdgcn_mfma_f32_16x16x32_bf16(kf, qf, z, 0, 0, 0);  // D[token][q]
    }
    float csum = 0.f;
#pragma unroll
    for (int f = 0; f < 4; f++) {
      unsigned short p0, p1, p2, p3;
      float e0 = __expf(sc[f][0]), e1 = __expf(sc[f][1]), e2 = __expf(sc[f][2]), e3 = __expf(sc[f][3]);
      csum += (e0 + e1) + (e2 + e3);
      p0 = f2bf(e0); p1 = f2bf(e1); p2 = f2bf(e2); p3 = f2bf(e3);
      u32x2 w;
      w.x = (unsigned)p0 | ((unsigned)p1 << 16);
      w.y = (unsigned)p2 | ((unsigned)p3 << 16);
      // PT[q=lr][token], swizzled: tokens f*16+lg*4 .. +3
      *(u32x2*)(pt + lr * 128 + ((((f * 2 + (lg >> 1)) ^ (lr & 7))) << 4) + (lg & 1) * 8) = w;
    }
    csum += __shfl_xor(csum, 16);
    csum += __shfl_xor(csum, 32);
    lsum += csum;
#pragma unroll
    for (int ks = 0; ks < 2; ks++) {
      short8 pf = *(const short8*)(pt + lr * 128 + (((ks * 4 + lg) ^ (lr & 7)) << 4));
      {
        short8 vf = *(const short8*)(vt + ((long)(b * 256 + h * HD_ + 0 + lr)) * 512 + t0 + ks * 32 + lg * 8);
        o0 = __builtin_amdgcn_mfma_f32_16x16x32_bf16(pf, vf, o0, 0, 0, 0);
      }
      {
        short8 vf = *(const short8*)(vt + ((long)(b * 256 + h * HD_ + 16 + lr)) * 512 + t0 + ks * 32 + lg * 8);
        o1 = __builtin_amdgcn_mfma_f32_16x16x32_bf16(pf, vf, o1, 0, 0, 0);
      }
    }
  }
#pragma unroll
  for (int r = 0; r < 4; r++) {
    float li = 1.0f / __shfl(lsum, lg * 4 + r);
    long rowoff = ((long)(b * L_ + q0 + lg * 4 + r)) * E_ + h * HD_;
    ctx[rowoff + lr] = o0[r] * li;
    ctx[rowoff + 16 + lr] = o1[r] * li;
  }
}

extern "C" void kernel_launch(void* const* d_in, const int* in_sizes, int n_in, void* d_out, int out_size, void* d_ws,
                              size_t ws_size, hipStream_t stream) {
  (void)in_sizes; (void)n_in; (void)out_size; (void)ws_size;
  const float* qs_in = (const float*)d_in[0];
  const float* ctx_in = (const float*)d_in[1];
  const int* rind = (const int*)d_in[2];
  const float* ipw = (const float*)d_in[3];
  const float* ipb = (const float*)d_in[4];
  const float* opw = (const float*)d_in[5];
  const float* opb = (const float*)d_in[6];
  const float* c1w = (const float*)d_in[7];
  const float* c1b = (const float*)d_in[8];
  const float* g1 = (const float*)d_in[9];
  const float* b1 = (const float*)d_in[10];
  const float* mu1 = (const float*)d_in[11];
  const float* v1 = (const float*)d_in[12];
  const float* c2w = (const float*)d_in[13];
  const float* c2b = (const float*)d_in[14];
  const float* g2 = (const float*)d_in[15];
  const float* b2 = (const float*)d_in[16];
  const float* mu2 = (const float*)d_in[17];
  const float* v2 = (const float*)d_in[18];
  float* out = (float*)d_out;
  float* ws = (float*)d_ws;

  // ---- workspace layout (float offsets), 75 MB total ----
  float* Kt = ws;                                  // [0, 4M)      -> later ctx
  float* Qt = ws + 4194304;                        // [4M, 8M)
  float* ctxb = ws;                                // reuse Kt region
  float* H = ws;                                   // [0, 8M) per MLP half (Kt+Qt dead)
  float* Qsbuf = ws + 8388608;                     // 2MB
  unsigned* md = (unsigned*)(ws + 8912896);        // 16KB
  unsigned* idxsel = (unsigned*)(ws + 9175040);    // 8KB
  float* ksel = ws + 9437184;                      // 2MB
  unsigned short* q_bf = (unsigned short*)(ws + 10485760);   // 8MB  (16384x256 bf16)
  unsigned short* kv_k = (unsigned short*)(ws + 12582912);   // 1MB  (2048x256 bf16)
  unsigned short* v_t = (unsigned short*)(ws + 12845056);    // 1MB  (4x256x512 bf16)
  float* Y = ws + 10485760;                        // 16MB, overlays q_bf/kv_k/v_t (dead by then)
  float* X = ws + 14680064;                        // 16MB
  unsigned short* wdu = (unsigned short*)(ws + 18874368);    // 3MB weight duos
  unsigned short* wq_d = wdu;                 // 256x512
  unsigned short* wkv_d = wdu + 131072;       // 512x512
  unsigned short* opw_d = wdu + 393216;       // 256x512
  unsigned short* c1w_d = wdu + 524288;       // 1024x512
  unsigned short* c2w_d = wdu + 1048576;      // 256x2048

  const float qscale = 0.17677669529663687f;  // 1/sqrt(32)

  // weight splits
  k_w2duo<<<64, 256, 0, stream>>>(ipw, wq_d, 65536, 256);
  k_w2duo<<<128, 256, 0, stream>>>(ipw + 65536, wkv_d, 131072, 256);
  k_w2duo<<<64, 256, 0, stream>>>(opw, opw_d, 65536, 256);
  k_w2duo<<<256, 256, 0, stream>>>(c1w, c1w_d, 262144, 256);
  k_w2duo<<<256, 256, 0, stream>>>(c2w, c2w_d, 262144, 1024);

  dim3 tb(32, 8);
  k_transpose<<<dim3(128, 8, 4), tb, 0, stream>>>(ctx_in, Kt);
  k_transpose<<<dim3(128, 8, 4), tb, 0, stream>>>(qs_in, Qt);
  k_init_md<<<64, 256, 0, stream>>>(md);
  k_gather_rows<<<512, 256, 0, stream>>>(Qt, rind, Qsbuf, TOPK_);
  k_dist<<<dim3(32, 4, 8), 256, 0, stream>>>(Kt, Qsbuf, md);
  k_sort<<<4, 1024, 0, stream>>>(md, idxsel);
  k_gather_rows<<<512, 256, 0, stream>>>(Kt, (const int*)idxsel, ksel, TOPK_);

  // q projection -> q_bf (bias + 1/sqrt(HD) folded, bf16)
  k_gemm_mfma<64, 0><<<dim3(4, 128), 256, 0, stream>>>(Qt, wq_d, nullptr, q_bf, nullptr, 256, 256, qscale, ipb,
                                                       nullptr, nullptr, nullptr, nullptr);
  // k/v projection -> kv_k (row-major) + v_t (transposed [b][d][t])
  k_gemm_mfma<64, 1><<<dim3(8, 16), 256, 0, stream>>>(ksel, wkv_d, nullptr, kv_k, v_t, 256, 512, 1.f, ipb + 256,
                                                      nullptr, nullptr, nullptr, nullptr);
  // fused MFMA attention -> ctxb fp32 (reuses Kt region)
  k_attn_mfma<<<dim3(64, NH_, B_), 256, 0, stream>>>(q_bf, kv_k, v_t, ctxb);
  // out projection -> X fp32
  k_gemm_mfma<64, 2><<<dim3(4, 128), 256, 0, stream>>>(ctxb, opw_d, X, nullptr, nullptr, 256, 256, 1.f, opb, nullptr,
                                                       nullptr, nullptr, nullptr);
  // MLP in halves: conv1(bn,relu) -> H ; conv2(bn) -> Y
  for (int half = 0; half < 2; half++) {
    const float* Xh = X + (long)half * 8192 * 256;
    float* Yh = Y + (long)half * 8192 * 256;
    k_gemm_mfma<128, 3><<<dim3(8, 64), 256, 0, stream>>>(Xh, c1w_d, H, nullptr, nullptr, 256, 1024, 1.f, c1b, g1, b1,
                                                         mu1, v1);
    k_gemm_mfma<64, 4><<<dim3(4, 64), 256, 0, stream>>>(H, c2w_d, Yh, nullptr, nullptr, 1024, 256, 1.f, c2b, g2, b2,
                                                        mu2, v2);
  }
  // residual add + transpose back to (B,C,H,W)
  k_final<<<dim3(128, 8, 4), tb, 0, stream>>>(X, Y, out);
}

// Round 3
// 403.049 us; speedup vs baseline: 2.1403x; 1.2736x over previous
//
#include <hip/hip_runtime.h>
#include <math.h>

#define B_ 4
#define C_ 256
#define L_ 4096
#define E_ 256
#define NH_ 8
#define HD_ 32
#define TOPK_ 512
#define MLP_ 1024
#define EPS_ 1e-5f

typedef __attribute__((ext_vector_type(4))) float f32x4;
typedef __attribute__((ext_vector_type(8))) short short8;
typedef __attribute__((ext_vector_type(2))) unsigned int u32x2;
typedef __attribute__((ext_vector_type(4))) unsigned int u32x4;

__device__ __forceinline__ unsigned short f2bf(float x) {
  unsigned u = __float_as_uint(x);
  return (unsigned short)((u + 0x7FFFu + ((u >> 16) & 1)) >> 16);
}
__device__ __forceinline__ float bf2f(unsigned short h) { return __uint_as_float((unsigned)h << 16); }

// ---------------- transpose (B,256,4096) -> (B,4096,256); optional bf16 copy ----------------
template <int WRITE_BF>
__global__ __launch_bounds__(256) void k_transpose(const float* __restrict__ in, float* __restrict__ out,
                                                   unsigned short* __restrict__ outbf) {
  __shared__ float tile[32][33];
  int b = blockIdx.z;
  int l0 = blockIdx.x * 32, c0 = blockIdx.y * 32;
  const float* ib = in + (long)b * C_ * L_;
  float* ob = out + (long)b * L_ * C_;
  int tx = threadIdx.x, ty = threadIdx.y;
#pragma unroll
  for (int i = ty; i < 32; i += 8) tile[i][tx] = ib[(long)(c0 + i) * L_ + l0 + tx];
  __syncthreads();
#pragma unroll
  for (int i = ty; i < 32; i += 8) {
    float v = tile[tx][i];
    long off = (long)(l0 + i) * C_ + c0 + tx;
    ob[off] = v;
    if (WRITE_BF) outbf[(long)b * L_ * C_ + off] = f2bf(v);
  }
}

// ---------------- gathers ----------------
__global__ __launch_bounds__(256) void k_gather_f32(const float* __restrict__ src, const int* __restrict__ ind,
                                                    float* __restrict__ dst, int nrows) {
  int gr = blockIdx.x * 4 + (threadIdx.x >> 6);
  int b = gr / nrows, r = gr % nrows;
  int c = (threadIdx.x & 63) * 4;
  int idx = ind[b * nrows + r];
  *(float4*)(dst + ((long)b * nrows + r) * C_ + c) = *(const float4*)(src + ((long)b * L_ + idx) * C_ + c);
}

__global__ __launch_bounds__(256) void k_gather_bf(const float* __restrict__ src, const int* __restrict__ ind,
                                                   unsigned short* __restrict__ dst, int nrows) {
  int gr = blockIdx.x * 4 + (threadIdx.x >> 6);
  int b = gr / nrows, r = gr % nrows;
  int c = (threadIdx.x & 63) * 4;
  int idx = ind[b * nrows + r];
  float4 x = *(const float4*)(src + ((long)b * L_ + idx) * C_ + c);
  u32x2 w;
  w.x = (unsigned)f2bf(x.x) | ((unsigned)f2bf(x.y) << 16);
  w.y = (unsigned)f2bf(x.z) | ((unsigned)f2bf(x.w) << 16);
  *(u32x2*)(dst + ((long)b * nrows + r) * C_ + c) = w;
}

__global__ void k_init_md(unsigned* md) { md[blockIdx.x * 256 + threadIdx.x] = 0x7f800000u; }

// ---------------- min-L1 distance v2: conflict-free, DS-light ----------------
// grid (64, B, 8). block 256. lane channel set = {4*cg + 32*i}, cg = tid&7. 2 tokens/thread.
__global__ __launch_bounds__(256) void k_dist(const float* __restrict__ Kt, const float* __restrict__ Qs,
                                              unsigned* __restrict__ mdbits) {
  __shared__ float Ql[32 * 256];  // 32KB
  const int b = blockIdx.y, tb = blockIdx.x, qz = blockIdx.z;
  const int tid = threadIdx.x;
  const int cg = tid & 7, slot = tid >> 3;  // slot 0..31
  const int T0 = tb * 64 + slot;
  const float* k0p = Kt + ((long)b * L_ + T0) * C_ + cg * 4;
  float4 K0[8], K1[8];
#pragma unroll
  for (int i = 0; i < 8; i++) {
    K0[i] = *(const float4*)(k0p + i * 32);
    K1[i] = *(const float4*)(k0p + 32 * C_ + i * 32);
  }
  float m0 = INFINITY, m1 = INFINITY;
  const int qrow = tid >> 3, qj = tid & 7;
  for (int qc = 0; qc < 2; qc++) {
    __syncthreads();
    const float* qsrc = Qs + ((long)b * TOPK_ + qz * 64 + qc * 32 + qrow) * C_;
#pragma unroll
    for (int i = 0; i < 8; i++)
      *(float4*)&Ql[qrow * 256 + qj * 4 + i * 32] = *(const float4*)(qsrc + qj * 4 + i * 32);
    __syncthreads();
    for (int q = 0; q < 32; q++) {
      const float* qp = &Ql[q * 256 + cg * 4];
      float a0 = 0, a1 = 0, a2 = 0, a3 = 0, b0 = 0, b1 = 0, b2 = 0, b3 = 0;
#pragma unroll
      for (int i = 0; i < 8; i++) {
        float4 qv = *(const float4*)(qp + i * 32);
        a0 += fabsf(K0[i].x - qv.x); a1 += fabsf(K0[i].y - qv.y);
        a2 += fabsf(K0[i].z - qv.z); a3 += fabsf(K0[i].w - qv.w);
        b0 += fabsf(K1[i].x - qv.x); b1 += fabsf(K1[i].y - qv.y);
        b2 += fabsf(K1[i].z - qv.z); b3 += fabsf(K1[i].w - qv.w);
      }
      float s0 = (a0 + a1) + (a2 + a3);
      float s1 = (b0 + b1) + (b2 + b3);
      s0 += __shfl_xor(s0, 1); s0 += __shfl_xor(s0, 2); s0 += __shfl_xor(s0, 4);
      s1 += __shfl_xor(s1, 1); s1 += __shfl_xor(s1, 2); s1 += __shfl_xor(s1, 4);
      m0 = fminf(m0, s0);
      m1 = fminf(m1, s1);
    }
  }
  if (cg == 0) {
    atomicMin(&mdbits[b * L_ + T0], __float_as_uint(m0));
    atomicMin(&mdbits[b * L_ + T0 + 32], __float_as_uint(m1));
  }
}

// ---------------- bitonic sort 4096 keys per batch; keep 512 smallest ----------------
__global__ __launch_bounds__(1024) void k_sort(const unsigned* __restrict__ mdb, unsigned* __restrict__ idxsel) {
  __shared__ unsigned long long s[4096];
  const int b = blockIdx.x, tid = threadIdx.x;
  for (int i = tid; i < 4096; i += 1024)
    s[i] = (((unsigned long long)mdb[b * L_ + i]) << 32) | (unsigned)i;
  __syncthreads();
  for (int k = 2; k <= 4096; k <<= 1)
    for (int j = k >> 1; j > 0; j >>= 1) {
      for (int i = tid; i < 4096; i += 1024) {
        int ixj = i ^ j;
        if (ixj > i) {
          bool up = ((i & k) == 0);
          unsigned long long a = s[i], c = s[ixj];
          if ((a > c) == up) { s[i] = c; s[ixj] = a; }
        }
      }
      __syncthreads();
    }
  for (int i = tid; i < TOPK_; i += 1024) idxsel[b * TOPK_ + i] = (unsigned)(s[i] & 0xFFFFFFFFu);
}

// ---------------- weight converts ----------------
__global__ __launch_bounds__(256) void k_w2bf(const float* __restrict__ W, unsigned short* __restrict__ D) {
  int i = (blockIdx.x * 256 + threadIdx.x) * 8;
  float4 x = *(const float4*)(W + i);
  float4 y = *(const float4*)(W + i + 4);
  u32x4 w;
  w.x = (unsigned)f2bf(x.x) | ((unsigned)f2bf(x.y) << 16);
  w.y = (unsigned)f2bf(x.z) | ((unsigned)f2bf(x.w) << 16);
  w.z = (unsigned)f2bf(y.x) | ((unsigned)f2bf(y.y) << 16);
  w.w = (unsigned)f2bf(y.z) | ((unsigned)f2bf(y.w) << 16);
  *(u32x4*)(D + i) = w;
}

// duo: D[n][(k>>5)*64 + (k&31)] = hi, +32 = lo
__global__ __launch_bounds__(256) void k_w2duo(const float* __restrict__ W, unsigned short* __restrict__ D,
                                               int total, int K) {
  int i = (blockIdx.x * 256 + threadIdx.x) * 4;
  if (i >= total) return;
  int n = i / K, k = i % K;
  float4 x = *(const float4*)(W + i);
  unsigned short h0 = f2bf(x.x), h1 = f2bf(x.y), h2 = f2bf(x.z), h3 = f2bf(x.w);
  unsigned short l0 = f2bf(x.x - bf2f(h0)), l1 = f2bf(x.y - bf2f(h1));
  unsigned short l2 = f2bf(x.z - bf2f(h2)), l3 = f2bf(x.w - bf2f(h3));
  u32x2 hv, lv;
  hv.x = (unsigned)h0 | ((unsigned)h1 << 16); hv.y = (unsigned)h2 | ((unsigned)h3 << 16);
  lv.x = (unsigned)l0 | ((unsigned)l1 << 16); lv.y = (unsigned)l2 | ((unsigned)l3 << 16);
  unsigned short* dst = D + (long)n * 2 * K + (k >> 5) * 64 + (k & 31);
  *(u32x2*)dst = hv;
  *(u32x2*)(dst + 32) = lv;
}

// ---------------- single-bf16 MFMA GEMM: C[m,n] = epi(sum_k A[m,k]*B[n,k]) ----------------
// A [M][K] bf16 row-major, B [N][K] bf16 row-major. K-step 64.
// MODE 0: (v+bias)*cscale -> bf16. MODE 1: kv dual out. MODE 3: bias+bn+relu -> bf16.
// MODE 5: bias+bn + Xres residual + transposed store -> fp32 out[b][c][l].
template <int BN, int MODE>
__global__ __launch_bounds__(256) void k_gemm_s(
    const unsigned short* __restrict__ A, const unsigned short* __restrict__ Bm, int K, int N, float cscale,
    const float* __restrict__ bias, const float* __restrict__ g, const float* __restrict__ be,
    const float* __restrict__ mu, const float* __restrict__ va, const float* __restrict__ Xres,
    float* __restrict__ Cf, unsigned short* __restrict__ Cb, unsigned short* __restrict__ Caux) {
  constexpr int NWN = (BN == 128) ? 2 : 1;
  constexpr int WR = (NWN == 2) ? 64 : 32;
  constexpr int MG = WR / 16, NG = 4;
  __shared__ __align__(16) unsigned short As[128 * 64];
  __shared__ __align__(16) unsigned short Bs[BN * 64];
  const int tid = threadIdx.x;
  const int wid = tid >> 6, lane = tid & 63, lr = lane & 15, lg = lane >> 4;
  const int wm = wid / NWN, wn = wid % NWN;
  const int row0 = wm * WR, col0 = wn * 64;
  char* AsB = (char*)As;
  char* BsB = (char*)Bs;
  f32x4 acc[MG][NG];
#pragma unroll
  for (int m = 0; m < MG; m++)
#pragma unroll
    for (int n = 0; n < NG; n++) acc[m][n] = (f32x4){0.f, 0.f, 0.f, 0.f};

  for (int k0 = 0; k0 < K; k0 += 64) {
    if (k0) __syncthreads();
    {  // stage A: 128 rows x 64 k (128B/row)
      int r = tid >> 1, h = tid & 1;
      const unsigned short* p = A + (long)(blockIdx.y * 128 + r) * K + k0 + h * 32;
#pragma unroll
      for (int j = 0; j < 4; j++) {
        u32x4 w = *(const u32x4*)(p + j * 8);
        int c = h * 4 + j;
        *(u32x4*)(AsB + r * 128 + ((c ^ (r & 7)) << 4)) = w;
      }
    }
    if (BN == 128) {
      int r = tid >> 1, h = tid & 1;
      const unsigned short* p = Bm + (long)(blockIdx.x * 128 + r) * K + k0 + h * 32;
#pragma unroll
      for (int j = 0; j < 4; j++) {
        u32x4 w = *(const u32x4*)(p + j * 8);
        int c = h * 4 + j;
        *(u32x4*)(BsB + r * 128 + ((c ^ (r & 7)) << 4)) = w;
      }
    } else {
      int r = tid >> 2, qp = tid & 3;
      const unsigned short* p = Bm + (long)(blockIdx.x * 64 + r) * K + k0 + qp * 16;
#pragma unroll
      for (int j = 0; j < 2; j++) {
        u32x4 w = *(const u32x4*)(p + j * 8);
        int c = qp * 2 + j;
        *(u32x4*)(BsB + r * 128 + ((c ^ (r & 7)) << 4)) = w;
      }
    }
    __syncthreads();
    short8 a0[MG], a1[MG], b0[NG], b1[NG];
#pragma unroll
    for (int m = 0; m < MG; m++) {
      int rr = row0 + m * 16 + lr;
      a0[m] = *(const short8*)(AsB + rr * 128 + (((0 + lg) ^ (rr & 7)) << 4));
      a1[m] = *(const short8*)(AsB + rr * 128 + (((4 + lg) ^ (rr & 7)) << 4));
    }
#pragma unroll
    for (int n = 0; n < NG; n++) {
      int rr = col0 + n * 16 + lr;
      b0[n] = *(const short8*)(BsB + rr * 128 + (((0 + lg) ^ (rr & 7)) << 4));
      b1[n] = *(const short8*)(BsB + rr * 128 + (((4 + lg) ^ (rr & 7)) << 4));
    }
#pragma unroll
    for (int m = 0; m < MG; m++)
#pragma unroll
      for (int n = 0; n < NG; n++)
        acc[m][n] = __builtin_amdgcn_mfma_f32_16x16x32_bf16(a0[m], b0[n], acc[m][n], 0, 0, 0);
#pragma unroll
    for (int m = 0; m < MG; m++)
#pragma unroll
      for (int n = 0; n < NG; n++)
        acc[m][n] = __builtin_amdgcn_mfma_f32_16x16x32_bf16(a1[m], b1[n], acc[m][n], 0, 0, 0);
  }
  const int mbase = blockIdx.y * 128 + row0 + lg * 4;
  const int nbase = blockIdx.x * BN + col0;
#pragma unroll
  for (int n = 0; n < NG; n++) {
    int nn = nbase + n * 16 + lr;
    float bb = bias[nn];
    float inv = 0.f, sh = 0.f;
    if (MODE == 3 || MODE == 5) {
      inv = g[nn] / sqrtf(va[nn] + EPS_);
      sh = be[nn] - mu[nn] * inv;
    }
#pragma unroll
    for (int m = 0; m < MG; m++) {
#pragma unroll
      for (int r = 0; r < 4; r++) {
        int mm = mbase + m * 16 + r;
        float v = acc[m][n][r] + bb;
        if (MODE == 0) {
          Cb[(long)mm * N + nn] = f2bf(v * cscale);
        } else if (MODE == 1) {
          if (nn < 256) {
            Cb[(long)mm * 256 + nn] = f2bf(v);
          } else {
            int bi = mm >> 9, t = mm & 511;
            Caux[((long)bi * 256 + (nn - 256)) * 512 + t] = f2bf(v);
          }
        } else if (MODE == 3) {
          v = v * inv + sh;
          v = fmaxf(v, 0.f);
          Cb[(long)mm * N + nn] = f2bf(v);
        } else if (MODE == 5) {
          v = v * inv + sh + Xres[(long)mm * 256 + nn];
          int bi = mm >> 12, l = mm & 4095;
          Cf[(long)bi * (C_ * L_) + (long)nn * L_ + l] = v;
        }
      }
    }
  }
}

// ---------------- duo MFMA GEMM (out-proj only): A duo [M][2K], B duo [N][2K] ----------------
// epilogue: X fp32 [m][256] + X_bf bf16 [m][256]
__global__ __launch_bounds__(256) void k_gemm_d(const unsigned short* __restrict__ A,
                                                const unsigned short* __restrict__ Bd, int K,
                                                const float* __restrict__ bias, float* __restrict__ Cf,
                                                unsigned short* __restrict__ Cb) {
  constexpr int MG = 2, NG = 4;
  __shared__ __align__(16) unsigned short As[128 * 64];
  __shared__ __align__(16) unsigned short Bs[64 * 64];
  const int tid = threadIdx.x;
  const int wid = tid >> 6, lane = tid & 63, lr = lane & 15, lg = lane >> 4;
  const int row0 = wid * 32;
  char* AsB = (char*)As;
  char* BsB = (char*)Bs;
  f32x4 acc[MG][NG];
#pragma unroll
  for (int m = 0; m < MG; m++)
#pragma unroll
    for (int n = 0; n < NG; n++) acc[m][n] = (f32x4){0.f, 0.f, 0.f, 0.f};

  for (int kb = 0; kb < K; kb += 32) {
    if (kb) __syncthreads();
    {
      int r = tid >> 1, h = tid & 1;
      const unsigned short* p = A + (long)(blockIdx.y * 128 + r) * (2 * K) + kb * 2 + h * 32;
#pragma unroll
      for (int j = 0; j < 4; j++) {
        u32x4 w = *(const u32x4*)(p + j * 8);
        int c = h * 4 + j;
        *(u32x4*)(AsB + r * 128 + ((c ^ (r & 7)) << 4)) = w;
      }
    }
    {
      int r = tid >> 2, qp = tid & 3;
      const unsigned short* p = Bd + (long)(blockIdx.x * 64 + r) * (2 * K) + kb * 2 + qp * 16;
#pragma unroll
      for (int j = 0; j < 2; j++) {
        u32x4 w = *(const u32x4*)(p + j * 8);
        int c = qp * 2 + j;
        *(u32x4*)(BsB + r * 128 + ((c ^ (r & 7)) << 4)) = w;
      }
    }
    __syncthreads();
    short8 a0[MG], a1[MG], b0[NG], b1[NG];
#pragma unroll
    for (int m = 0; m < MG; m++) {
      int rr = row0 + m * 16 + lr;
      a0[m] = *(const short8*)(AsB + rr * 128 + (((0 + lg) ^ (rr & 7)) << 4));
      a1[m] = *(const short8*)(AsB + rr * 128 + (((4 + lg) ^ (rr & 7)) << 4));
    }
#pragma unroll
    for (int n = 0; n < NG; n++) {
      int rr = n * 16 + lr;
      b0[n] = *(const short8*)(BsB + rr * 128 + (((0 + lg) ^ (rr & 7)) << 4));
      b1[n] = *(const short8*)(BsB + rr * 128 + (((4 + lg) ^ (rr & 7)) << 4));
    }
#pragma unroll
    for (int m = 0; m < MG; m++)
#pragma unroll
      for (int n = 0; n < NG; n++)
        acc[m][n] = __builtin_amdgcn_mfma_f32_16x16x32_bf16(a0[m], b0[n], acc[m][n], 0, 0, 0);
#pragma unroll
    for (int m = 0; m < MG; m++)
#pragma unroll
      for (int n = 0; n < NG; n++)
        acc[m][n] = __builtin_amdgcn_mfma_f32_16x16x32_bf16(a1[m], b0[n], acc[m][n], 0, 0, 0);
#pragma unroll
    for (int m = 0; m < MG; m++)
#pragma unroll
      for (int n = 0; n < NG; n++)
        acc[m][n] = __builtin_amdgcn_mfma_f32_16x16x32_bf16(a0[m], b1[n], acc[m][n], 0, 0, 0);
  }
  const int mbase = blockIdx.y * 128 + row0 + lg * 4;
  const int nbase = blockIdx.x * 64;
#pragma unroll
  for (int n = 0; n < NG; n++) {
    int nn = nbase + n * 16 + lr;
    float bb = bias[nn];
#pragma unroll
    for (int m = 0; m < MG; m++) {
#pragma unroll
      for (int r = 0; r < 4; r++) {
        int mm = mbase + m * 16 + r;
        float v = acc[m][n][r] + bb;
        Cf[(long)mm * 256 + nn] = v;
        Cb[(long)mm * 256 + nn] = f2bf(v);
      }
    }
  }
}

// ---------------- MFMA flash attention; epilogue writes ctx in duo layout ----------------
__global__ __launch_bounds__(256) void k_attn_mfma(const unsigned short* __restrict__ qbf,
                                                   const unsigned short* __restrict__ kvk,
                                                   const unsigned short* __restrict__ vt,
                                                   unsigned short* __restrict__ ctxd) {
  __shared__ __align__(16) unsigned short PT[4 * 1024];
  const int tid = threadIdx.x, wid = tid >> 6, lane = tid & 63, lr = lane & 15, lg = lane >> 4;
  const int b = blockIdx.z, h = blockIdx.y;
  const int q0 = blockIdx.x * 64 + wid * 16;
  char* pt = (char*)(PT + wid * 1024);
  short8 qf = *(const short8*)(qbf + ((long)(b * L_ + q0 + lr)) * E_ + h * HD_ + lg * 8);
  f32x4 o0 = (f32x4){0.f, 0.f, 0.f, 0.f}, o1 = (f32x4){0.f, 0.f, 0.f, 0.f};
  float lsum = 0.f;
  for (int t0 = 0; t0 < TOPK_; t0 += 64) {
    f32x4 sc[4];
#pragma unroll
    for (int f = 0; f < 4; f++) {
      short8 kf = *(const short8*)(kvk + ((long)(b * TOPK_ + t0 + f * 16 + lr)) * E_ + h * HD_ + lg * 8);
      f32x4 z = (f32x4){0.f, 0.f, 0.f, 0.f};
      sc[f] = __builtin_amdgcn_mfma_f32_16x16x32_bf16(kf, qf, z, 0, 0, 0);  // D[token][q]
    }
    float csum = 0.f;
#pragma unroll
    for (int f = 0; f < 4; f++) {
      float e0 = __expf(sc[f][0]), e1 = __expf(sc[f][1]), e2 = __expf(sc[f][2]), e3 = __expf(sc[f][3]);
      csum += (e0 + e1) + (e2 + e3);
      u32x2 w;
      w.x = (unsigned)f2bf(e0) | ((unsigned)f2bf(e1) << 16);
      w.y = (unsigned)f2bf(e2) | ((unsigned)f2bf(e3) << 16);
      *(u32x2*)(pt + lr * 128 + ((((f * 2 + (lg >> 1)) ^ (lr & 7))) << 4) + (lg & 1) * 8) = w;
    }
    csum += __shfl_xor(csum, 16);
    csum += __shfl_xor(csum, 32);
    lsum += csum;
#pragma unroll
    for (int ks = 0; ks < 2; ks++) {
      short8 pf = *(const short8*)(pt + lr * 128 + (((ks * 4 + lg) ^ (lr & 7)) << 4));
      {
        short8 vf = *(const short8*)(vt + ((long)(b * 256 + h * HD_ + 0 + lr)) * 512 + t0 + ks * 32 + lg * 8);
        o0 = __builtin_amdgcn_mfma_f32_16x16x32_bf16(pf, vf, o0, 0, 0, 0);
      }
      {
        short8 vf = *(const short8*)(vt + ((long)(b * 256 + h * HD_ + 16 + lr)) * 512 + t0 + ks * 32 + lg * 8);
        o1 = __builtin_amdgcn_mfma_f32_16x16x32_bf16(pf, vf, o1, 0, 0, 0);
      }
    }
  }
#pragma unroll
  for (int r = 0; r < 4; r++) {
    float li = 1.0f / __shfl(lsum, lg * 4 + r);
    long base = ((long)(b * L_ + q0 + lg * 4 + r)) * 512 + h * 64;
    float v0 = o0[r] * li, v1 = o1[r] * li;
    unsigned short h0 = f2bf(v0), h1 = f2bf(v1);
    ctxd[base + lr] = h0;
    ctxd[base + 32 + lr] = f2bf(v0 - bf2f(h0));
    ctxd[base + 16 + lr] = h1;
    ctxd[base + 48 + lr] = f2bf(v1 - bf2f(h1));
  }
}

extern "C" void kernel_launch(void* const* d_in, const int* in_sizes, int n_in, void* d_out, int out_size, void* d_ws,
                              size_t ws_size, hipStream_t stream) {
  (void)in_sizes; (void)n_in; (void)out_size; (void)ws_size;
  const float* qs_in = (const float*)d_in[0];
  const float* ctx_in = (const float*)d_in[1];
  const int* rind = (const int*)d_in[2];
  const float* ipw = (const float*)d_in[3];
  const float* ipb = (const float*)d_in[4];
  const float* opw = (const float*)d_in[5];
  const float* opb = (const float*)d_in[6];
  const float* c1w = (const float*)d_in[7];
  const float* c1b = (const float*)d_in[8];
  const float* g1 = (const float*)d_in[9];
  const float* b1 = (const float*)d_in[10];
  const float* mu1 = (const float*)d_in[11];
  const float* v1 = (const float*)d_in[12];
  const float* c2w = (const float*)d_in[13];
  const float* c2b = (const float*)d_in[14];
  const float* g2 = (const float*)d_in[15];
  const float* b2 = (const float*)d_in[16];
  const float* mu2 = (const float*)d_in[17];
  const float* v2 = (const float*)d_in[18];
  float* out = (float*)d_out;
  float* ws = (float*)d_ws;

  // ---- workspace layout (float offsets; 1MB = 262144 floats), peak ~74MB ----
  float* Qt = ws;                                             // [0,16)MB fp32; dead after Qsbuf gather
  unsigned short* ctxd = (unsigned short*)ws;                 // [0,16) duo, written by attn
  float* Kt = ws + 4194304;                                   // [16,32) fp32; dead after ksel gather
  float* X = ws + 4194304;                                    // [16,32) fp32, written by out-proj
  unsigned short* Qt_bf = (unsigned short*)(ws + 8388608);    // [32,40) bf16; dead after q-proj
  unsigned short* X_bf = (unsigned short*)(ws + 8388608);     // [32,40) bf16, written by out-proj
  float* Qsbuf = ws + 10485760;                               // [40,42)
  unsigned* md = (unsigned*)(ws + 11010048);                  // [42,42.06)
  unsigned* idxsel = (unsigned*)(ws + 11026432);              // 8KB
  unsigned short* ksel_bf = (unsigned short*)(ws + 11272192); // [43,44)
  unsigned short* q_bf = (unsigned short*)(ws + 11534336);    // [44,52)
  unsigned short* kv_k = (unsigned short*)(ws + 13631488);    // [52,53)
  unsigned short* v_t = (unsigned short*)(ws + 13893632);     // [53,54)
  unsigned short* H = (unsigned short*)(ws + 10485760);       // [40,72) bf16 hidden (overlays dead bufs)
  unsigned short* wq_bf = (unsigned short*)(ws + 18874368);   // [72,...)
  unsigned short* wkv_bf = (unsigned short*)(ws + 18907136);
  unsigned short* c1w_bf = (unsigned short*)(ws + 18972672);
  unsigned short* c2w_bf = (unsigned short*)(ws + 19103744);
  unsigned short* opw_d = (unsigned short*)(ws + 19234816);

  const float qscale = 0.17677669529663687f;  // 1/sqrt(32)

  // weight converts
  k_w2bf<<<32, 256, 0, stream>>>(ipw, wq_bf);
  k_w2bf<<<64, 256, 0, stream>>>(ipw + 65536, wkv_bf);
  k_w2bf<<<128, 256, 0, stream>>>(c1w, c1w_bf);
  k_w2bf<<<128, 256, 0, stream>>>(c2w, c2w_bf);
  k_w2duo<<<64, 256, 0, stream>>>(opw, opw_d, 65536, 256);

  dim3 tb(32, 8);
  k_transpose<1><<<dim3(128, 8, 4), tb, 0, stream>>>(qs_in, Qt, Qt_bf);
  k_transpose<0><<<dim3(128, 8, 4), tb, 0, stream>>>(ctx_in, Kt, nullptr);
  k_init_md<<<64, 256, 0, stream>>>(md);
  k_gather_f32<<<512, 256, 0, stream>>>(Qt, rind, Qsbuf, TOPK_);
  k_dist<<<dim3(64, 4, 8), 256, 0, stream>>>(Kt, Qsbuf, md);
  k_sort<<<4, 1024, 0, stream>>>(md, idxsel);
  k_gather_bf<<<512, 256, 0, stream>>>(Kt, (const int*)idxsel, ksel_bf, TOPK_);

  // q projection -> q_bf (bias + 1/sqrt(HD) folded)
  k_gemm_s<64, 0><<<dim3(4, 128), 256, 0, stream>>>(Qt_bf, wq_bf, 256, 256, qscale, ipb, nullptr, nullptr, nullptr,
                                                    nullptr, nullptr, nullptr, q_bf, nullptr);
  // k/v projection -> kv_k + v_t
  k_gemm_s<64, 1><<<dim3(8, 16), 256, 0, stream>>>(ksel_bf, wkv_bf, 256, 512, 1.f, ipb + 256, nullptr, nullptr,
                                                   nullptr, nullptr, nullptr, nullptr, kv_k, v_t);
  // attention -> ctx duo
  k_attn_mfma<<<dim3(64, NH_, B_), 256, 0, stream>>>(q_bf, kv_k, v_t, ctxd);
  // out projection (duo x duo) -> X fp32 + X_bf
  k_gemm_d<<<dim3(4, 128), 256, 0, stream>>>(ctxd, opw_d, 256, opb, X, X_bf);
  // conv1 + bn + relu -> H bf16
  k_gemm_s<128, 3><<<dim3(8, 128), 256, 0, stream>>>(X_bf, c1w_bf, 256, 1024, 1.f, c1b, g1, b1, mu1, v1, nullptr,
                                                     nullptr, H, nullptr);
  // conv2 + bn + residual + transpose -> out
  k_gemm_s<64, 5><<<dim3(4, 128), 256, 0, stream>>>(H, c2w_bf, 1024, 256, 1.f, c2b, g2, b2, mu2, v2, X, out,
                                                    nullptr, nullptr);
}

// Round 4
// 390.485 us; speedup vs baseline: 2.2092x; 1.0322x over previous
//
#include <hip/hip_runtime.h>
#include <math.h>

#define B_ 4
#define C_ 256
#define L_ 4096
#define E_ 256
#define NH_ 8
#define HD_ 32
#define TOPK_ 512
#define MLP_ 1024
#define EPS_ 1e-5f

typedef __attribute__((ext_vector_type(4))) float f32x4;
typedef __attribute__((ext_vector_type(8))) short short8;
typedef __attribute__((ext_vector_type(2))) unsigned int u32x2;
typedef __attribute__((ext_vector_type(4))) unsigned int u32x4;

__device__ __forceinline__ unsigned short f2bf(float x) {
  unsigned u = __float_as_uint(x);
  return (unsigned short)((u + 0x7FFFu + ((u >> 16) & 1)) >> 16);
}
__device__ __forceinline__ float bf2f(unsigned short h) { return __uint_as_float((unsigned)h << 16); }

// ---------------- transpose (B,256,4096) -> (B,4096,256); optional bf16 copy ----------------
template <int WRITE_BF>
__global__ __launch_bounds__(256) void k_transpose(const float* __restrict__ in, float* __restrict__ out,
                                                   unsigned short* __restrict__ outbf) {
  __shared__ float tile[32][33];
  int b = blockIdx.z;
  int l0 = blockIdx.x * 32, c0 = blockIdx.y * 32;
  const float* ib = in + (long)b * C_ * L_;
  float* ob = out + (long)b * L_ * C_;
  int tx = threadIdx.x, ty = threadIdx.y;
#pragma unroll
  for (int i = ty; i < 32; i += 8) tile[i][tx] = ib[(long)(c0 + i) * L_ + l0 + tx];
  __syncthreads();
#pragma unroll
  for (int i = ty; i < 32; i += 8) {
    float v = tile[tx][i];
    long off = (long)(l0 + i) * C_ + c0 + tx;
    ob[off] = v;
    if (WRITE_BF) outbf[(long)b * L_ * C_ + off] = f2bf(v);
  }
}

// ---------------- prep: all weight converts + md init in ONE launch ----------------
__device__ __forceinline__ void conv_bf8(const float* __restrict__ W, unsigned short* __restrict__ D, int blk) {
  int i = (blk * 256 + threadIdx.x) * 8;
  float4 x = *(const float4*)(W + i);
  float4 y = *(const float4*)(W + i + 4);
  u32x4 w;
  w.x = (unsigned)f2bf(x.x) | ((unsigned)f2bf(x.y) << 16);
  w.y = (unsigned)f2bf(x.z) | ((unsigned)f2bf(x.w) << 16);
  w.z = (unsigned)f2bf(y.x) | ((unsigned)f2bf(y.y) << 16);
  w.w = (unsigned)f2bf(y.z) | ((unsigned)f2bf(y.w) << 16);
  *(u32x4*)(D + i) = w;
}

__global__ __launch_bounds__(256) void k_prep(const float* __restrict__ ipw, const float* __restrict__ opw,
                                              const float* __restrict__ c1w, const float* __restrict__ c2w,
                                              unsigned short* __restrict__ wq_bf, unsigned short* __restrict__ wkv_bf,
                                              unsigned short* __restrict__ c1w_bf, unsigned short* __restrict__ c2w_bf,
                                              unsigned short* __restrict__ opw_d, unsigned* __restrict__ md) {
  int bx = blockIdx.x;
  if (bx < 32) {
    conv_bf8(ipw, wq_bf, bx);
  } else if (bx < 96) {
    conv_bf8(ipw + 65536, wkv_bf, bx - 32);
  } else if (bx < 224) {
    conv_bf8(c1w, c1w_bf, bx - 96);
  } else if (bx < 352) {
    conv_bf8(c2w, c2w_bf, bx - 224);
  } else if (bx < 416) {
    // opw duo: 4 elems/thread
    int i = ((bx - 352) * 256 + threadIdx.x) * 4;
    int k = i & 255;  // K=256
    int n = i >> 8;
    float4 x = *(const float4*)(opw + i);
    unsigned short h0 = f2bf(x.x), h1 = f2bf(x.y), h2 = f2bf(x.z), h3 = f2bf(x.w);
    unsigned short l0 = f2bf(x.x - bf2f(h0)), l1 = f2bf(x.y - bf2f(h1));
    unsigned short l2 = f2bf(x.z - bf2f(h2)), l3 = f2bf(x.w - bf2f(h3));
    u32x2 hv, lv;
    hv.x = (unsigned)h0 | ((unsigned)h1 << 16); hv.y = (unsigned)h2 | ((unsigned)h3 << 16);
    lv.x = (unsigned)l0 | ((unsigned)l1 << 16); lv.y = (unsigned)l2 | ((unsigned)l3 << 16);
    unsigned short* dst = opw_d + (long)n * 512 + (k >> 5) * 64 + (k & 31);
    *(u32x2*)dst = hv;
    *(u32x2*)(dst + 32) = lv;
  } else {
    md[(bx - 416) * 256 + threadIdx.x] = 0x7f800000u;
  }
}

// ---------------- gathers ----------------
__global__ __launch_bounds__(256) void k_gather_f32(const float* __restrict__ src, const int* __restrict__ ind,
                                                    float* __restrict__ dst, int nrows) {
  int gr = blockIdx.x * 4 + (threadIdx.x >> 6);
  int b = gr / nrows, r = gr % nrows;
  int c = (threadIdx.x & 63) * 4;
  int idx = ind[b * nrows + r];
  *(float4*)(dst + ((long)b * nrows + r) * C_ + c) = *(const float4*)(src + ((long)b * L_ + idx) * C_ + c);
}

__global__ __launch_bounds__(256) void k_gather_bf(const float* __restrict__ src, const int* __restrict__ ind,
                                                   unsigned short* __restrict__ dst, int nrows) {
  int gr = blockIdx.x * 4 + (threadIdx.x >> 6);
  int b = gr / nrows, r = gr % nrows;
  int c = (threadIdx.x & 63) * 4;
  int idx = ind[b * nrows + r];
  float4 x = *(const float4*)(src + ((long)b * L_ + idx) * C_ + c);
  u32x2 w;
  w.x = (unsigned)f2bf(x.x) | ((unsigned)f2bf(x.y) << 16);
  w.y = (unsigned)f2bf(x.z) | ((unsigned)f2bf(x.w) << 16);
  *(u32x2*)(dst + ((long)b * nrows + r) * C_ + c) = w;
}

// ---------------- min-L1 distance: conflict-free, K resident in VGPRs ----------------
// grid (64, B, 8). block 256, >=128 VGPRs via launch_bounds min-waves=4.
// lane channel set = {4*cg + 32*i}, cg = tid&7; 2 tokens/thread (64 K floats in regs).
__global__ __launch_bounds__(256, 4) void k_dist(const float* __restrict__ Kt, const float* __restrict__ Qs,
                                                 unsigned* __restrict__ mdbits) {
  __shared__ float Ql[32 * 256];  // 32KB
  const int b = blockIdx.y, tb = blockIdx.x, qz = blockIdx.z;
  const int tid = threadIdx.x;
  const int cg = tid & 7, slot = tid >> 3;  // slot 0..31
  const int T0 = tb * 64 + slot;
  const float* k0p = Kt + ((long)b * L_ + T0) * C_ + cg * 4;
  float4 K0[8], K1[8];
#pragma unroll
  for (int i = 0; i < 8; i++) {
    K0[i] = *(const float4*)(k0p + i * 32);
    K1[i] = *(const float4*)(k0p + 32 * C_ + i * 32);
  }
  float m0 = INFINITY, m1 = INFINITY;
  const int qrow = tid >> 3, qj = tid & 7;
  for (int qc = 0; qc < 2; qc++) {
    __syncthreads();
    const float* qsrc = Qs + ((long)b * TOPK_ + qz * 64 + qc * 32 + qrow) * C_;
#pragma unroll
    for (int i = 0; i < 8; i++)
      *(float4*)&Ql[qrow * 256 + qj * 4 + i * 32] = *(const float4*)(qsrc + qj * 4 + i * 32);
    __syncthreads();
    for (int q = 0; q < 32; q++) {
      const float* qp = &Ql[q * 256 + cg * 4];
      float a0 = 0, a1 = 0, a2 = 0, a3 = 0, b0 = 0, b1 = 0, b2 = 0, b3 = 0;
#pragma unroll
      for (int i = 0; i < 8; i++) {
        float4 qv = *(const float4*)(qp + i * 32);
        a0 += fabsf(K0[i].x - qv.x); a1 += fabsf(K0[i].y - qv.y);
        a2 += fabsf(K0[i].z - qv.z); a3 += fabsf(K0[i].w - qv.w);
        b0 += fabsf(K1[i].x - qv.x); b1 += fabsf(K1[i].y - qv.y);
        b2 += fabsf(K1[i].z - qv.z); b3 += fabsf(K1[i].w - qv.w);
      }
      float s0 = (a0 + a1) + (a2 + a3);
      float s1 = (b0 + b1) + (b2 + b3);
      s0 += __shfl_xor(s0, 1); s0 += __shfl_xor(s0, 2); s0 += __shfl_xor(s0, 4);
      s1 += __shfl_xor(s1, 1); s1 += __shfl_xor(s1, 2); s1 += __shfl_xor(s1, 4);
      m0 = fminf(m0, s0);
      m1 = fminf(m1, s1);
    }
  }
  if (cg == 0) {
    atomicMin(&mdbits[b * L_ + T0], __float_as_uint(m0));
    atomicMin(&mdbits[b * L_ + T0 + 32], __float_as_uint(m1));
  }
}

// ---------------- bitonic sort 4096 keys per batch; keep 512 smallest ----------------
__global__ __launch_bounds__(1024) void k_sort(const unsigned* __restrict__ mdb, unsigned* __restrict__ idxsel) {
  __shared__ unsigned long long s[4096];
  const int b = blockIdx.x, tid = threadIdx.x;
  for (int i = tid; i < 4096; i += 1024)
    s[i] = (((unsigned long long)mdb[b * L_ + i]) << 32) | (unsigned)i;
  __syncthreads();
  for (int k = 2; k <= 4096; k <<= 1)
    for (int j = k >> 1; j > 0; j >>= 1) {
      for (int i = tid; i < 4096; i += 1024) {
        int ixj = i ^ j;
        if (ixj > i) {
          bool up = ((i & k) == 0);
          unsigned long long a = s[i], c = s[ixj];
          if ((a > c) == up) { s[i] = c; s[ixj] = a; }
        }
      }
      __syncthreads();
    }
  for (int i = tid; i < TOPK_; i += 1024) idxsel[b * TOPK_ + i] = (unsigned)(s[i] & 0xFFFFFFFFu);
}

// ---------------- single-bf16 MFMA GEMM: C[m,n] = epi(sum_k A[m,k]*B[n,k]) ----------------
// MODE 0: (v+bias)*cscale -> bf16. MODE 1: kv dual out. MODE 3: bias+bn+relu -> bf16.
// MODE 5: bias+bn + Xres residual + transposed store -> fp32 out[b][c][l].
template <int BN, int MODE>
__global__ __launch_bounds__(256) void k_gemm_s(
    const unsigned short* __restrict__ A, const unsigned short* __restrict__ Bm, int K, int N, float cscale,
    const float* __restrict__ bias, const float* __restrict__ g, const float* __restrict__ be,
    const float* __restrict__ mu, const float* __restrict__ va, const float* __restrict__ Xres,
    float* __restrict__ Cf, unsigned short* __restrict__ Cb, unsigned short* __restrict__ Caux) {
  constexpr int NWN = (BN == 128) ? 2 : 1;
  constexpr int WR = (NWN == 2) ? 64 : 32;
  constexpr int MG = WR / 16, NG = 4;
  __shared__ __align__(16) unsigned short As[128 * 64];
  __shared__ __align__(16) unsigned short Bs[BN * 64];
  const int tid = threadIdx.x;
  const int wid = tid >> 6, lane = tid & 63, lr = lane & 15, lg = lane >> 4;
  const int wm = wid / NWN, wn = wid % NWN;
  const int row0 = wm * WR, col0 = wn * 64;
  char* AsB = (char*)As;
  char* BsB = (char*)Bs;
  f32x4 acc[MG][NG];
#pragma unroll
  for (int m = 0; m < MG; m++)
#pragma unroll
    for (int n = 0; n < NG; n++) acc[m][n] = (f32x4){0.f, 0.f, 0.f, 0.f};

  for (int k0 = 0; k0 < K; k0 += 64) {
    if (k0) __syncthreads();
    {  // stage A: 128 rows x 64 k (128B/row)
      int r = tid >> 1, h = tid & 1;
      const unsigned short* p = A + (long)(blockIdx.y * 128 + r) * K + k0 + h * 32;
#pragma unroll
      for (int j = 0; j < 4; j++) {
        u32x4 w = *(const u32x4*)(p + j * 8);
        int c = h * 4 + j;
        *(u32x4*)(AsB + r * 128 + ((c ^ (r & 7)) << 4)) = w;
      }
    }
    if (BN == 128) {
      int r = tid >> 1, h = tid & 1;
      const unsigned short* p = Bm + (long)(blockIdx.x * 128 + r) * K + k0 + h * 32;
#pragma unroll
      for (int j = 0; j < 4; j++) {
        u32x4 w = *(const u32x4*)(p + j * 8);
        int c = h * 4 + j;
        *(u32x4*)(BsB + r * 128 + ((c ^ (r & 7)) << 4)) = w;
      }
    } else {
      int r = tid >> 2, qp = tid & 3;
      const unsigned short* p = Bm + (long)(blockIdx.x * 64 + r) * K + k0 + qp * 16;
#pragma unroll
      for (int j = 0; j < 2; j++) {
        u32x4 w = *(const u32x4*)(p + j * 8);
        int c = qp * 2 + j;
        *(u32x4*)(BsB + r * 128 + ((c ^ (r & 7)) << 4)) = w;
      }
    }
    __syncthreads();
    short8 a0[MG], a1[MG], b0[NG], b1[NG];
#pragma unroll
    for (int m = 0; m < MG; m++) {
      int rr = row0 + m * 16 + lr;
      a0[m] = *(const short8*)(AsB + rr * 128 + (((0 + lg) ^ (rr & 7)) << 4));
      a1[m] = *(const short8*)(AsB + rr * 128 + (((4 + lg) ^ (rr & 7)) << 4));
    }
#pragma unroll
    for (int n = 0; n < NG; n++) {
      int rr = col0 + n * 16 + lr;
      b0[n] = *(const short8*)(BsB + rr * 128 + (((0 + lg) ^ (rr & 7)) << 4));
      b1[n] = *(const short8*)(BsB + rr * 128 + (((4 + lg) ^ (rr & 7)) << 4));
    }
#pragma unroll
    for (int m = 0; m < MG; m++)
#pragma unroll
      for (int n = 0; n < NG; n++)
        acc[m][n] = __builtin_amdgcn_mfma_f32_16x16x32_bf16(a0[m], b0[n], acc[m][n], 0, 0, 0);
#pragma unroll
    for (int m = 0; m < MG; m++)
#pragma unroll
      for (int n = 0; n < NG; n++)
        acc[m][n] = __builtin_amdgcn_mfma_f32_16x16x32_bf16(a1[m], b1[n], acc[m][n], 0, 0, 0);
  }
  const int mbase = blockIdx.y * 128 + row0 + lg * 4;
  const int nbase = blockIdx.x * BN + col0;
#pragma unroll
  for (int n = 0; n < NG; n++) {
    int nn = nbase + n * 16 + lr;
    float bb = bias[nn];
    float inv = 0.f, sh = 0.f;
    if (MODE == 3 || MODE == 5) {
      inv = g[nn] / sqrtf(va[nn] + EPS_);
      sh = be[nn] - mu[nn] * inv;
    }
#pragma unroll
    for (int m = 0; m < MG; m++) {
#pragma unroll
      for (int r = 0; r < 4; r++) {
        int mm = mbase + m * 16 + r;
        float v = acc[m][n][r] + bb;
        if (MODE == 0) {
          Cb[(long)mm * N + nn] = f2bf(v * cscale);
        } else if (MODE == 1) {
          if (nn < 256) {
            Cb[(long)mm * 256 + nn] = f2bf(v);
          } else {
            int bi = mm >> 9, t = mm & 511;
            Caux[((long)bi * 256 + (nn - 256)) * 512 + t] = f2bf(v);
          }
        } else if (MODE == 3) {
          v = v * inv + sh;
          v = fmaxf(v, 0.f);
          Cb[(long)mm * N + nn] = f2bf(v);
        } else if (MODE == 5) {
          v = v * inv + sh + Xres[(long)mm * 256 + nn];
          int bi = mm >> 12, l = mm & 4095;
          Cf[(long)bi * (C_ * L_) + (long)nn * L_ + l] = v;
        }
      }
    }
  }
}

// ---------------- duo MFMA GEMM (out-proj only): A duo [M][2K], B duo [N][2K] ----------------
__global__ __launch_bounds__(256) void k_gemm_d(const unsigned short* __restrict__ A,
                                                const unsigned short* __restrict__ Bd, int K,
                                                const float* __restrict__ bias, float* __restrict__ Cf,
                                                unsigned short* __restrict__ Cb) {
  constexpr int MG = 2, NG = 4;
  __shared__ __align__(16) unsigned short As[128 * 64];
  __shared__ __align__(16) unsigned short Bs[64 * 64];
  const int tid = threadIdx.x;
  const int wid = tid >> 6, lane = tid & 63, lr = lane & 15, lg = lane >> 4;
  const int row0 = wid * 32;
  char* AsB = (char*)As;
  char* BsB = (char*)Bs;
  f32x4 acc[MG][NG];
#pragma unroll
  for (int m = 0; m < MG; m++)
#pragma unroll
    for (int n = 0; n < NG; n++) acc[m][n] = (f32x4){0.f, 0.f, 0.f, 0.f};

  for (int kb = 0; kb < K; kb += 32) {
    if (kb) __syncthreads();
    {
      int r = tid >> 1, h = tid & 1;
      const unsigned short* p = A + (long)(blockIdx.y * 128 + r) * (2 * K) + kb * 2 + h * 32;
#pragma unroll
      for (int j = 0; j < 4; j++) {
        u32x4 w = *(const u32x4*)(p + j * 8);
        int c = h * 4 + j;
        *(u32x4*)(AsB + r * 128 + ((c ^ (r & 7)) << 4)) = w;
      }
    }
    {
      int r = tid >> 2, qp = tid & 3;
      const unsigned short* p = Bd + (long)(blockIdx.x * 64 + r) * (2 * K) + kb * 2 + qp * 16;
#pragma unroll
      for (int j = 0; j < 2; j++) {
        u32x4 w = *(const u32x4*)(p + j * 8);
        int c = qp * 2 + j;
        *(u32x4*)(BsB + r * 128 + ((c ^ (r & 7)) << 4)) = w;
      }
    }
    __syncthreads();
    short8 a0[MG], a1[MG], b0[NG], b1[NG];
#pragma unroll
    for (int m = 0; m < MG; m++) {
      int rr = row0 + m * 16 + lr;
      a0[m] = *(const short8*)(AsB + rr * 128 + (((0 + lg) ^ (rr & 7)) << 4));
      a1[m] = *(const short8*)(AsB + rr * 128 + (((4 + lg) ^ (rr & 7)) << 4));
    }
#pragma unroll
    for (int n = 0; n < NG; n++) {
      int rr = n * 16 + lr;
      b0[n] = *(const short8*)(BsB + rr * 128 + (((0 + lg) ^ (rr & 7)) << 4));
      b1[n] = *(const short8*)(BsB + rr * 128 + (((4 + lg) ^ (rr & 7)) << 4));
    }
#pragma unroll
    for (int m = 0; m < MG; m++)
#pragma unroll
      for (int n = 0; n < NG; n++)
        acc[m][n] = __builtin_amdgcn_mfma_f32_16x16x32_bf16(a0[m], b0[n], acc[m][n], 0, 0, 0);
#pragma unroll
    for (int m = 0; m < MG; m++)
#pragma unroll
      for (int n = 0; n < NG; n++)
        acc[m][n] = __builtin_amdgcn_mfma_f32_16x16x32_bf16(a1[m], b0[n], acc[m][n], 0, 0, 0);
#pragma unroll
    for (int m = 0; m < MG; m++)
#pragma unroll
      for (int n = 0; n < NG; n++)
        acc[m][n] = __builtin_amdgcn_mfma_f32_16x16x32_bf16(a0[m], b1[n], acc[m][n], 0, 0, 0);
  }
  const int mbase = blockIdx.y * 128 + row0 + lg * 4;
  const int nbase = blockIdx.x * 64;
#pragma unroll
  for (int n = 0; n < NG; n++) {
    int nn = nbase + n * 16 + lr;
    float bb = bias[nn];
#pragma unroll
    for (int m = 0; m < MG; m++) {
#pragma unroll
      for (int r = 0; r < 4; r++) {
        int mm = mbase + m * 16 + r;
        float v = acc[m][n][r] + bb;
        Cf[(long)mm * 256 + nn] = v;
        Cb[(long)mm * 256 + nn] = f2bf(v);
      }
    }
  }
}

// ---------------- MFMA flash attention; epilogue writes ctx in duo layout ----------------
__global__ __launch_bounds__(256) void k_attn_mfma(const unsigned short* __restrict__ qbf,
                                                   const unsigned short* __restrict__ kvk,
                                                   const unsigned short* __restrict__ vt,
                                                   unsigned short* __restrict__ ctxd) {
  __shared__ __align__(16) unsigned short PT[4 * 1024];
  const int tid = threadIdx.x, wid = tid >> 6, lane = tid & 63, lr = lane & 15, lg = lane >> 4;
  const int b = blockIdx.z, h = blockIdx.y;
  const int q0 = blockIdx.x * 64 + wid * 16;
  char* pt = (char*)(PT + wid * 1024);
  short8 qf = *(const short8*)(qbf + ((long)(b * L_ + q0 + lr)) * E_ + h * HD_ + lg * 8);
  f32x4 o0 = (f32x4){0.f, 0.f, 0.f, 0.f}, o1 = (f32x4){0.f, 0.f, 0.f, 0.f};
  float lsum = 0.f;
  for (int t0 = 0; t0 < TOPK_; t0 += 64) {
    f32x4 sc[4];
#pragma unroll
    for (int f = 0; f < 4; f++) {
      short8 kf = *(const short8*)(kvk + ((long)(b * TOPK_ + t0 + f * 16 + lr)) * E_ + h * HD_ + lg * 8);
      f32x4 z = (f32x4){0.f, 0.f, 0.f, 0.f};
      sc[f] = __builtin_amdgcn_mfma_f32_16x16x32_bf16(kf, qf, z, 0, 0, 0);  // D[token][q]
    }
    float csum = 0.f;
#pragma unroll
    for (int f = 0; f < 4; f++) {
      float e0 = __expf(sc[f][0]), e1 = __expf(sc[f][1]), e2 = __expf(sc[f][2]), e3 = __expf(sc[f][3]);
      csum += (e0 + e1) + (e2 + e3);
      u32x2 w;
      w.x = (unsigned)f2bf(e0) | ((unsigned)f2bf(e1) << 16);
      w.y = (unsigned)f2bf(e2) | ((unsigned)f2bf(e3) << 16);
      *(u32x2*)(pt + lr * 128 + ((((f * 2 + (lg >> 1)) ^ (lr & 7))) << 4) + (lg & 1) * 8) = w;
    }
    csum += __shfl_xor(csum, 16);
    csum += __shfl_xor(csum, 32);
    lsum += csum;
#pragma unroll
    for (int ks = 0; ks < 2; ks++) {
      short8 pf = *(const short8*)(pt + lr * 128 + (((ks * 4 + lg) ^ (lr & 7)) << 4));
      {
        short8 vf = *(const short8*)(vt + ((long)(b * 256 + h * HD_ + 0 + lr)) * 512 + t0 + ks * 32 + lg * 8);
        o0 = __builtin_amdgcn_mfma_f32_16x16x32_bf16(pf, vf, o0, 0, 0, 0);
      }
      {
        short8 vf = *(const short8*)(vt + ((long)(b * 256 + h * HD_ + 16 + lr)) * 512 + t0 + ks * 32 + lg * 8);
        o1 = __builtin_amdgcn_mfma_f32_16x16x32_bf16(pf, vf, o1, 0, 0, 0);
      }
    }
  }
#pragma unroll
  for (int r = 0; r < 4; r++) {
    float li = 1.0f / __shfl(lsum, lg * 4 + r);
    long base = ((long)(b * L_ + q0 + lg * 4 + r)) * 512 + h * 64;
    float v0 = o0[r] * li, v1 = o1[r] * li;
    unsigned short h0 = f2bf(v0), h1 = f2bf(v1);
    ctxd[base + lr] = h0;
    ctxd[base + 32 + lr] = f2bf(v0 - bf2f(h0));
    ctxd[base + 16 + lr] = h1;
    ctxd[base + 48 + lr] = f2bf(v1 - bf2f(h1));
  }
}

extern "C" void kernel_launch(void* const* d_in, const int* in_sizes, int n_in, void* d_out, int out_size, void* d_ws,
                              size_t ws_size, hipStream_t stream) {
  (void)in_sizes; (void)n_in; (void)out_size; (void)ws_size;
  const float* qs_in = (const float*)d_in[0];
  const float* ctx_in = (const float*)d_in[1];
  const int* rind = (const int*)d_in[2];
  const float* ipw = (const float*)d_in[3];
  const float* ipb = (const float*)d_in[4];
  const float* opw = (const float*)d_in[5];
  const float* opb = (const float*)d_in[6];
  const float* c1w = (const float*)d_in[7];
  const float* c1b = (const float*)d_in[8];
  const float* g1 = (const float*)d_in[9];
  const float* b1 = (const float*)d_in[10];
  const float* mu1 = (const float*)d_in[11];
  const float* v1 = (const float*)d_in[12];
  const float* c2w = (const float*)d_in[13];
  const float* c2b = (const float*)d_in[14];
  const float* g2 = (const float*)d_in[15];
  const float* b2 = (const float*)d_in[16];
  const float* mu2 = (const float*)d_in[17];
  const float* v2 = (const float*)d_in[18];
  float* out = (float*)d_out;
  float* ws = (float*)d_ws;

  // ---- workspace layout (float offsets; 1MB = 262144 floats), peak ~74MB ----
  float* Qt = ws;                                             // [0,16)MB fp32; dead after Qsbuf gather
  unsigned short* ctxd = (unsigned short*)ws;                 // [0,16) duo, written by attn
  float* Kt = ws + 4194304;                                   // [16,32) fp32; dead after ksel gather
  float* X = ws + 4194304;                                    // [16,32) fp32, written by out-proj
  unsigned short* Qt_bf = (unsigned short*)(ws + 8388608);    // [32,40) bf16; dead after q-proj
  unsigned short* X_bf = (unsigned short*)(ws + 8388608);     // [32,40) bf16, written by out-proj
  float* Qsbuf = ws + 10485760;                               // [40,42)
  unsigned* md = (unsigned*)(ws + 11010048);                  // [42,42.06)
  unsigned* idxsel = (unsigned*)(ws + 11026432);              // 8KB
  unsigned short* ksel_bf = (unsigned short*)(ws + 11272192); // [43,44)
  unsigned short* q_bf = (unsigned short*)(ws + 11534336);    // [44,52)
  unsigned short* kv_k = (unsigned short*)(ws + 13631488);    // [52,53)
  unsigned short* v_t = (unsigned short*)(ws + 13893632);     // [53,54)
  unsigned short* H = (unsigned short*)(ws + 10485760);       // [40,72) bf16 hidden (overlays dead bufs)
  unsigned short* wq_bf = (unsigned short*)(ws + 18874368);   // [72,...)
  unsigned short* wkv_bf = (unsigned short*)(ws + 18907136);
  unsigned short* c1w_bf = (unsigned short*)(ws + 18972672);
  unsigned short* c2w_bf = (unsigned short*)(ws + 19103744);
  unsigned short* opw_d = (unsigned short*)(ws + 19234816);

  const float qscale = 0.17677669529663687f;  // 1/sqrt(32)

  // all weight converts + md init in one launch
  k_prep<<<480, 256, 0, stream>>>(ipw, opw, c1w, c2w, wq_bf, wkv_bf, c1w_bf, c2w_bf, opw_d, md);

  dim3 tb(32, 8);
  k_transpose<1><<<dim3(128, 8, 4), tb, 0, stream>>>(qs_in, Qt, Qt_bf);
  k_transpose<0><<<dim3(128, 8, 4), tb, 0, stream>>>(ctx_in, Kt, nullptr);
  k_gather_f32<<<512, 256, 0, stream>>>(Qt, rind, Qsbuf, TOPK_);
  k_dist<<<dim3(64, 4, 8), 256, 0, stream>>>(Kt, Qsbuf, md);
  k_sort<<<4, 1024, 0, stream>>>(md, idxsel);
  k_gather_bf<<<512, 256, 0, stream>>>(Kt, (const int*)idxsel, ksel_bf, TOPK_);

  // q projection -> q_bf (bias + 1/sqrt(HD) folded)
  k_gemm_s<64, 0><<<dim3(4, 128), 256, 0, stream>>>(Qt_bf, wq_bf, 256, 256, qscale, ipb, nullptr, nullptr, nullptr,
                                                    nullptr, nullptr, nullptr, q_bf, nullptr);
  // k/v projection -> kv_k + v_t
  k_gemm_s<64, 1><<<dim3(8, 16), 256, 0, stream>>>(ksel_bf, wkv_bf, 256, 512, 1.f, ipb + 256, nullptr, nullptr,
                                                   nullptr, nullptr, nullptr, nullptr, kv_k, v_t);
  // attention -> ctx duo
  k_attn_mfma<<<dim3(64, NH_, B_), 256, 0, stream>>>(q_bf, kv_k, v_t, ctxd);
  // out projection (duo x duo) -> X fp32 + X_bf
  k_gemm_d<<<dim3(4, 128), 256, 0, stream>>>(ctxd, opw_d, 256, opb, X, X_bf);
  // conv1 + bn + relu -> H bf16
  k_gemm_s<128, 3><<<dim3(8, 128), 256, 0, stream>>>(X_bf, c1w_bf, 256, 1024, 1.f, c1b, g1, b1, mu1, v1, nullptr,
                                                     nullptr, H, nullptr);
  // conv2 + bn + residual + transpose -> out
  k_gemm_s<64, 5><<<dim3(4, 128), 256, 0, stream>>>(H, c2w_bf, 1024, 256, 1.f, c2b, g2, b2, mu2, v2, X, out,
                                                    nullptr, nullptr);
}

// Round 5
// 384.848 us; speedup vs baseline: 2.2416x; 1.0146x over previous
//
#include <hip/hip_runtime.h>
#include <math.h>

#define B_ 4
#define C_ 256
#define L_ 4096
#define E_ 256
#define NH_ 8
#define HD_ 32
#define TOPK_ 512
#define MLP_ 1024
#define EPS_ 1e-5f

typedef __attribute__((ext_vector_type(4))) float f32x4;
typedef __attribute__((ext_vector_type(8))) short short8;
typedef __attribute__((ext_vector_type(2))) unsigned int u32x2;
typedef __attribute__((ext_vector_type(4))) unsigned int u32x4;

__device__ __forceinline__ unsigned short f2bf(float x) {
  unsigned u = __float_as_uint(x);
  return (unsigned short)((u + 0x7FFFu + ((u >> 16) & 1)) >> 16);
}
__device__ __forceinline__ float bf2f(unsigned short h) { return __uint_as_float((unsigned)h << 16); }

// ---------------- transpose (B,256,4096) -> (B,4096,256); optional bf16 copy ----------------
template <int WRITE_BF>
__global__ __launch_bounds__(256) void k_transpose(const float* __restrict__ in, float* __restrict__ out,
                                                   unsigned short* __restrict__ outbf) {
  __shared__ float tile[32][33];
  int b = blockIdx.z;
  int l0 = blockIdx.x * 32, c0 = blockIdx.y * 32;
  const float* ib = in + (long)b * C_ * L_;
  float* ob = out + (long)b * L_ * C_;
  int tx = threadIdx.x, ty = threadIdx.y;
#pragma unroll
  for (int i = ty; i < 32; i += 8) tile[i][tx] = ib[(long)(c0 + i) * L_ + l0 + tx];
  __syncthreads();
#pragma unroll
  for (int i = ty; i < 32; i += 8) {
    float v = tile[tx][i];
    long off = (long)(l0 + i) * C_ + c0 + tx;
    ob[off] = v;
    if (WRITE_BF) outbf[(long)b * L_ * C_ + off] = f2bf(v);
  }
}

// ---------------- prep: all weight converts + md init in ONE launch ----------------
__device__ __forceinline__ void conv_bf8(const float* __restrict__ W, unsigned short* __restrict__ D, int blk) {
  int i = (blk * 256 + threadIdx.x) * 8;
  float4 x = *(const float4*)(W + i);
  float4 y = *(const float4*)(W + i + 4);
  u32x4 w;
  w.x = (unsigned)f2bf(x.x) | ((unsigned)f2bf(x.y) << 16);
  w.y = (unsigned)f2bf(x.z) | ((unsigned)f2bf(x.w) << 16);
  w.z = (unsigned)f2bf(y.x) | ((unsigned)f2bf(y.y) << 16);
  w.w = (unsigned)f2bf(y.z) | ((unsigned)f2bf(y.w) << 16);
  *(u32x4*)(D + i) = w;
}

__global__ __launch_bounds__(256) void k_prep(const float* __restrict__ ipw, const float* __restrict__ opw,
                                              const float* __restrict__ c1w, const float* __restrict__ c2w,
                                              unsigned short* __restrict__ wq_bf, unsigned short* __restrict__ wkv_bf,
                                              unsigned short* __restrict__ c1w_bf, unsigned short* __restrict__ c2w_bf,
                                              unsigned short* __restrict__ opw_d, unsigned* __restrict__ md) {
  int bx = blockIdx.x;
  if (bx < 32) {
    conv_bf8(ipw, wq_bf, bx);
  } else if (bx < 96) {
    conv_bf8(ipw + 65536, wkv_bf, bx - 32);
  } else if (bx < 224) {
    conv_bf8(c1w, c1w_bf, bx - 96);
  } else if (bx < 352) {
    conv_bf8(c2w, c2w_bf, bx - 224);
  } else if (bx < 416) {
    // opw duo: 4 elems/thread
    int i = ((bx - 352) * 256 + threadIdx.x) * 4;
    int k = i & 255;  // K=256
    int n = i >> 8;
    float4 x = *(const float4*)(opw + i);
    unsigned short h0 = f2bf(x.x), h1 = f2bf(x.y), h2 = f2bf(x.z), h3 = f2bf(x.w);
    unsigned short l0 = f2bf(x.x - bf2f(h0)), l1 = f2bf(x.y - bf2f(h1));
    unsigned short l2 = f2bf(x.z - bf2f(h2)), l3 = f2bf(x.w - bf2f(h3));
    u32x2 hv, lv;
    hv.x = (unsigned)h0 | ((unsigned)h1 << 16); hv.y = (unsigned)h2 | ((unsigned)h3 << 16);
    lv.x = (unsigned)l0 | ((unsigned)l1 << 16); lv.y = (unsigned)l2 | ((unsigned)l3 << 16);
    unsigned short* dst = opw_d + (long)n * 512 + (k >> 5) * 64 + (k & 31);
    *(u32x2*)dst = hv;
    *(u32x2*)(dst + 32) = lv;
  } else {
    md[(bx - 416) * 256 + threadIdx.x] = 0x7f800000u;
  }
}

// ---------------- gathers ----------------
__global__ __launch_bounds__(256) void k_gather_f32(const float* __restrict__ src, const int* __restrict__ ind,
                                                    float* __restrict__ dst, int nrows) {
  int gr = blockIdx.x * 4 + (threadIdx.x >> 6);
  int b = gr / nrows, r = gr % nrows;
  int c = (threadIdx.x & 63) * 4;
  int idx = ind[b * nrows + r];
  *(float4*)(dst + ((long)b * nrows + r) * C_ + c) = *(const float4*)(src + ((long)b * L_ + idx) * C_ + c);
}

__global__ __launch_bounds__(256) void k_gather_bf(const float* __restrict__ src, const int* __restrict__ ind,
                                                   unsigned short* __restrict__ dst, int nrows) {
  int gr = blockIdx.x * 4 + (threadIdx.x >> 6);
  int b = gr / nrows, r = gr % nrows;
  int c = (threadIdx.x & 63) * 4;
  int idx = ind[b * nrows + r];
  float4 x = *(const float4*)(src + ((long)b * L_ + idx) * C_ + c);
  u32x2 w;
  w.x = (unsigned)f2bf(x.x) | ((unsigned)f2bf(x.y) << 16);
  w.y = (unsigned)f2bf(x.z) | ((unsigned)f2bf(x.w) << 16);
  *(u32x2*)(dst + ((long)b * nrows + r) * C_ + c) = w;
}

// ---------------- min-L1 distance: conflict-free, K resident in VGPRs ----------------
// grid (64, B, 8). block 256. waves_per_eu(4,4) caps occupancy at 4 waves/SIMD so the
// allocator has a 128-VGPR budget and keeps K0/K1 (64 floats) in ArchVGPRs (r4: heuristic
// chose 64 VGPRs and shuffled K through AGPRs -> 2.4x VALU inflation).
// lane channel set = {4*cg + 32*i}, cg = tid&7; 2 tokens/thread.
__global__ __launch_bounds__(256) __attribute__((amdgpu_waves_per_eu(4, 4)))
void k_dist(const float* __restrict__ Kt, const float* __restrict__ Qs, unsigned* __restrict__ mdbits) {
  __shared__ float Ql[32 * 256];  // 32KB
  const int b = blockIdx.y, tb = blockIdx.x, qz = blockIdx.z;
  const int tid = threadIdx.x;
  const int cg = tid & 7, slot = tid >> 3;  // slot 0..31
  const int T0 = tb * 64 + slot;
  const float* k0p = Kt + ((long)b * L_ + T0) * C_ + cg * 4;
  float4 K0[8], K1[8];
#pragma unroll
  for (int i = 0; i < 8; i++) {
    K0[i] = *(const float4*)(k0p + i * 32);
    K1[i] = *(const float4*)(k0p + 32 * C_ + i * 32);
  }
  float m0 = INFINITY, m1 = INFINITY;
  const int qrow = tid >> 3, qj = tid & 7;
  for (int qc = 0; qc < 2; qc++) {
    __syncthreads();
    const float* qsrc = Qs + ((long)b * TOPK_ + qz * 64 + qc * 32 + qrow) * C_;
#pragma unroll
    for (int i = 0; i < 8; i++)
      *(float4*)&Ql[qrow * 256 + qj * 4 + i * 32] = *(const float4*)(qsrc + qj * 4 + i * 32);
    __syncthreads();
    for (int q = 0; q < 32; q++) {
      const float* qp = &Ql[q * 256 + cg * 4];
      float a0 = 0, a1 = 0, a2 = 0, a3 = 0, b0 = 0, b1 = 0, b2 = 0, b3 = 0;
#pragma unroll
      for (int i = 0; i < 8; i++) {
        float4 qv = *(const float4*)(qp + i * 32);
        a0 += fabsf(K0[i].x - qv.x); a1 += fabsf(K0[i].y - qv.y);
        a2 += fabsf(K0[i].z - qv.z); a3 += fabsf(K0[i].w - qv.w);
        b0 += fabsf(K1[i].x - qv.x); b1 += fabsf(K1[i].y - qv.y);
        b2 += fabsf(K1[i].z - qv.z); b3 += fabsf(K1[i].w - qv.w);
      }
      float s0 = (a0 + a1) + (a2 + a3);
      float s1 = (b0 + b1) + (b2 + b3);
      s0 += __shfl_xor(s0, 1); s0 += __shfl_xor(s0, 2); s0 += __shfl_xor(s0, 4);
      s1 += __shfl_xor(s1, 1); s1 += __shfl_xor(s1, 2); s1 += __shfl_xor(s1, 4);
      m0 = fminf(m0, s0);
      m1 = fminf(m1, s1);
    }
  }
  if (cg == 0) {
    atomicMin(&mdbits[b * L_ + T0], __float_as_uint(m0));
    atomicMin(&mdbits[b * L_ + T0 + 32], __float_as_uint(m1));
  }
}

// ---------------- bitonic sort 4096 keys per batch; keep 512 smallest ----------------
__global__ __launch_bounds__(1024) void k_sort(const unsigned* __restrict__ mdb, unsigned* __restrict__ idxsel) {
  __shared__ unsigned long long s[4096];
  const int b = blockIdx.x, tid = threadIdx.x;
  for (int i = tid; i < 4096; i += 1024)
    s[i] = (((unsigned long long)mdb[b * L_ + i]) << 32) | (unsigned)i;
  __syncthreads();
  for (int k = 2; k <= 4096; k <<= 1)
    for (int j = k >> 1; j > 0; j >>= 1) {
      for (int i = tid; i < 4096; i += 1024) {
        int ixj = i ^ j;
        if (ixj > i) {
          bool up = ((i & k) == 0);
          unsigned long long a = s[i], c = s[ixj];
          if ((a > c) == up) { s[i] = c; s[ixj] = a; }
        }
      }
      __syncthreads();
    }
  for (int i = tid; i < TOPK_; i += 1024) idxsel[b * TOPK_ + i] = (unsigned)(s[i] & 0xFFFFFFFFu);
}

// ---------------- single-bf16 MFMA GEMM: C[m,n] = epi(sum_k A[m,k]*B[n,k]) ----------------
// MODE 0: (v+bias)*cscale -> bf16. MODE 1: kv dual out. MODE 3: bias+bn+relu -> bf16.
// MODE 5: bias+bn + Xres residual + transposed store -> fp32 out[b][c][l].
template <int BN, int MODE>
__global__ __launch_bounds__(256) void k_gemm_s(
    const unsigned short* __restrict__ A, const unsigned short* __restrict__ Bm, int K, int N, float cscale,
    const float* __restrict__ bias, const float* __restrict__ g, const float* __restrict__ be,
    const float* __restrict__ mu, const float* __restrict__ va, const float* __restrict__ Xres,
    float* __restrict__ Cf, unsigned short* __restrict__ Cb, unsigned short* __restrict__ Caux) {
  constexpr int NWN = (BN == 128) ? 2 : 1;
  constexpr int WR = (NWN == 2) ? 64 : 32;
  constexpr int MG = WR / 16, NG = 4;
  __shared__ __align__(16) unsigned short As[128 * 64];
  __shared__ __align__(16) unsigned short Bs[BN * 64];
  const int tid = threadIdx.x;
  const int wid = tid >> 6, lane = tid & 63, lr = lane & 15, lg = lane >> 4;
  const int wm = wid / NWN, wn = wid % NWN;
  const int row0 = wm * WR, col0 = wn * 64;
  char* AsB = (char*)As;
  char* BsB = (char*)Bs;
  f32x4 acc[MG][NG];
#pragma unroll
  for (int m = 0; m < MG; m++)
#pragma unroll
    for (int n = 0; n < NG; n++) acc[m][n] = (f32x4){0.f, 0.f, 0.f, 0.f};

  for (int k0 = 0; k0 < K; k0 += 64) {
    if (k0) __syncthreads();
    {  // stage A: 128 rows x 64 k (128B/row)
      int r = tid >> 1, h = tid & 1;
      const unsigned short* p = A + (long)(blockIdx.y * 128 + r) * K + k0 + h * 32;
#pragma unroll
      for (int j = 0; j < 4; j++) {
        u32x4 w = *(const u32x4*)(p + j * 8);
        int c = h * 4 + j;
        *(u32x4*)(AsB + r * 128 + ((c ^ (r & 7)) << 4)) = w;
      }
    }
    if (BN == 128) {
      int r = tid >> 1, h = tid & 1;
      const unsigned short* p = Bm + (long)(blockIdx.x * 128 + r) * K + k0 + h * 32;
#pragma unroll
      for (int j = 0; j < 4; j++) {
        u32x4 w = *(const u32x4*)(p + j * 8);
        int c = h * 4 + j;
        *(u32x4*)(BsB + r * 128 + ((c ^ (r & 7)) << 4)) = w;
      }
    } else {
      int r = tid >> 2, qp = tid & 3;
      const unsigned short* p = Bm + (long)(blockIdx.x * 64 + r) * K + k0 + qp * 16;
#pragma unroll
      for (int j = 0; j < 2; j++) {
        u32x4 w = *(const u32x4*)(p + j * 8);
        int c = qp * 2 + j;
        *(u32x4*)(BsB + r * 128 + ((c ^ (r & 7)) << 4)) = w;
      }
    }
    __syncthreads();
    short8 a0[MG], a1[MG], b0[NG], b1[NG];
#pragma unroll
    for (int m = 0; m < MG; m++) {
      int rr = row0 + m * 16 + lr;
      a0[m] = *(const short8*)(AsB + rr * 128 + (((0 + lg) ^ (rr & 7)) << 4));
      a1[m] = *(const short8*)(AsB + rr * 128 + (((4 + lg) ^ (rr & 7)) << 4));
    }
#pragma unroll
    for (int n = 0; n < NG; n++) {
      int rr = col0 + n * 16 + lr;
      b0[n] = *(const short8*)(BsB + rr * 128 + (((0 + lg) ^ (rr & 7)) << 4));
      b1[n] = *(const short8*)(BsB + rr * 128 + (((4 + lg) ^ (rr & 7)) << 4));
    }
#pragma unroll
    for (int m = 0; m < MG; m++)
#pragma unroll
      for (int n = 0; n < NG; n++)
        acc[m][n] = __builtin_amdgcn_mfma_f32_16x16x32_bf16(a0[m], b0[n], acc[m][n], 0, 0, 0);
#pragma unroll
    for (int m = 0; m < MG; m++)
#pragma unroll
      for (int n = 0; n < NG; n++)
        acc[m][n] = __builtin_amdgcn_mfma_f32_16x16x32_bf16(a1[m], b1[n], acc[m][n], 0, 0, 0);
  }
  const int mbase = blockIdx.y * 128 + row0 + lg * 4;
  const int nbase = blockIdx.x * BN + col0;
#pragma unroll
  for (int n = 0; n < NG; n++) {
    int nn = nbase + n * 16 + lr;
    float bb = bias[nn];
    float inv = 0.f, sh = 0.f;
    if (MODE == 3 || MODE == 5) {
      inv = g[nn] / sqrtf(va[nn] + EPS_);
      sh = be[nn] - mu[nn] * inv;
    }
#pragma unroll
    for (int m = 0; m < MG; m++) {
#pragma unroll
      for (int r = 0; r < 4; r++) {
        int mm = mbase + m * 16 + r;
        float v = acc[m][n][r] + bb;
        if (MODE == 0) {
          Cb[(long)mm * N + nn] = f2bf(v * cscale);
        } else if (MODE == 1) {
          if (nn < 256) {
            Cb[(long)mm * 256 + nn] = f2bf(v);
          } else {
            int bi = mm >> 9, t = mm & 511;
            Caux[((long)bi * 256 + (nn - 256)) * 512 + t] = f2bf(v);
          }
        } else if (MODE == 3) {
          v = v * inv + sh;
          v = fmaxf(v, 0.f);
          Cb[(long)mm * N + nn] = f2bf(v);
        } else if (MODE == 5) {
          v = v * inv + sh + Xres[(long)mm * 256 + nn];
          int bi = mm >> 12, l = mm & 4095;
          Cf[(long)bi * (C_ * L_) + (long)nn * L_ + l] = v;
        }
      }
    }
  }
}

// ---------------- duo MFMA GEMM (out-proj only): A duo [M][2K], B duo [N][2K] ----------------
__global__ __launch_bounds__(256) void k_gemm_d(const unsigned short* __restrict__ A,
                                                const unsigned short* __restrict__ Bd, int K,
                                                const float* __restrict__ bias, float* __restrict__ Cf,
                                                unsigned short* __restrict__ Cb) {
  constexpr int MG = 2, NG = 4;
  __shared__ __align__(16) unsigned short As[128 * 64];
  __shared__ __align__(16) unsigned short Bs[64 * 64];
  const int tid = threadIdx.x;
  const int wid = tid >> 6, lane = tid & 63, lr = lane & 15, lg = lane >> 4;
  const int row0 = wid * 32;
  char* AsB = (char*)As;
  char* BsB = (char*)Bs;
  f32x4 acc[MG][NG];
#pragma unroll
  for (int m = 0; m < MG; m++)
#pragma unroll
    for (int n = 0; n < NG; n++) acc[m][n] = (f32x4){0.f, 0.f, 0.f, 0.f};

  for (int kb = 0; kb < K; kb += 32) {
    if (kb) __syncthreads();
    {
      int r = tid >> 1, h = tid & 1;
      const unsigned short* p = A + (long)(blockIdx.y * 128 + r) * (2 * K) + kb * 2 + h * 32;
#pragma unroll
      for (int j = 0; j < 4; j++) {
        u32x4 w = *(const u32x4*)(p + j * 8);
        int c = h * 4 + j;
        *(u32x4*)(AsB + r * 128 + ((c ^ (r & 7)) << 4)) = w;
      }
    }
    {
      int r = tid >> 2, qp = tid & 3;
      const unsigned short* p = Bd + (long)(blockIdx.x * 64 + r) * (2 * K) + kb * 2 + qp * 16;
#pragma unroll
      for (int j = 0; j < 2; j++) {
        u32x4 w = *(const u32x4*)(p + j * 8);
        int c = qp * 2 + j;
        *(u32x4*)(BsB + r * 128 + ((c ^ (r & 7)) << 4)) = w;
      }
    }
    __syncthreads();
    short8 a0[MG], a1[MG], b0[NG], b1[NG];
#pragma unroll
    for (int m = 0; m < MG; m++) {
      int rr = row0 + m * 16 + lr;
      a0[m] = *(const short8*)(AsB + rr * 128 + (((0 + lg) ^ (rr & 7)) << 4));
      a1[m] = *(const short8*)(AsB + rr * 128 + (((4 + lg) ^ (rr & 7)) << 4));
    }
#pragma unroll
    for (int n = 0; n < NG; n++) {
      int rr = n * 16 + lr;
      b0[n] = *(const short8*)(BsB + rr * 128 + (((0 + lg) ^ (rr & 7)) << 4));
      b1[n] = *(const short8*)(BsB + rr * 128 + (((4 + lg) ^ (rr & 7)) << 4));
    }
#pragma unroll
    for (int m = 0; m < MG; m++)
#pragma unroll
      for (int n = 0; n < NG; n++)
        acc[m][n] = __builtin_amdgcn_mfma_f32_16x16x32_bf16(a0[m], b0[n], acc[m][n], 0, 0, 0);
#pragma unroll
    for (int m = 0; m < MG; m++)
#pragma unroll
      for (int n = 0; n < NG; n++)
        acc[m][n] = __builtin_amdgcn_mfma_f32_16x16x32_bf16(a1[m], b0[n], acc[m][n], 0, 0, 0);
#pragma unroll
    for (int m = 0; m < MG; m++)
#pragma unroll
      for (int n = 0; n < NG; n++)
        acc[m][n] = __builtin_amdgcn_mfma_f32_16x16x32_bf16(a0[m], b1[n], acc[m][n], 0, 0, 0);
  }
  const int mbase = blockIdx.y * 128 + row0 + lg * 4;
  const int nbase = blockIdx.x * 64;
#pragma unroll
  for (int n = 0; n < NG; n++) {
    int nn = nbase + n * 16 + lr;
    float bb = bias[nn];
#pragma unroll
    for (int m = 0; m < MG; m++) {
#pragma unroll
      for (int r = 0; r < 4; r++) {
        int mm = mbase + m * 16 + r;
        float v = acc[m][n][r] + bb;
        Cf[(long)mm * 256 + nn] = v;
        Cb[(long)mm * 256 + nn] = f2bf(v);
      }
    }
  }
}

// ---------------- MFMA flash attention; epilogue writes ctx in duo layout ----------------
__global__ __launch_bounds__(256) void k_attn_mfma(const unsigned short* __restrict__ qbf,
                                                   const unsigned short* __restrict__ kvk,
                                                   const unsigned short* __restrict__ vt,
                                                   unsigned short* __restrict__ ctxd) {
  __shared__ __align__(16) unsigned short PT[4 * 1024];
  const int tid = threadIdx.x, wid = tid >> 6, lane = tid & 63, lr = lane & 15, lg = lane >> 4;
  const int b = blockIdx.z, h = blockIdx.y;
  const int q0 = blockIdx.x * 64 + wid * 16;
  char* pt = (char*)(PT + wid * 1024);
  short8 qf = *(const short8*)(qbf + ((long)(b * L_ + q0 + lr)) * E_ + h * HD_ + lg * 8);
  f32x4 o0 = (f32x4){0.f, 0.f, 0.f, 0.f}, o1 = (f32x4){0.f, 0.f, 0.f, 0.f};
  float lsum = 0.f;
  for (int t0 = 0; t0 < TOPK_; t0 += 64) {
    f32x4 sc[4];
#pragma unroll
    for (int f = 0; f < 4; f++) {
      short8 kf = *(const short8*)(kvk + ((long)(b * TOPK_ + t0 + f * 16 + lr)) * E_ + h * HD_ + lg * 8);
      f32x4 z = (f32x4){0.f, 0.f, 0.f, 0.f};
      sc[f] = __builtin_amdgcn_mfma_f32_16x16x32_bf16(kf, qf, z, 0, 0, 0);  // D[token][q]
    }
    float csum = 0.f;
#pragma unroll
    for (int f = 0; f < 4; f++) {
      float e0 = __expf(sc[f][0]), e1 = __expf(sc[f][1]), e2 = __expf(sc[f][2]), e3 = __expf(sc[f][3]);
      csum += (e0 + e1) + (e2 + e3);
      u32x2 w;
      w.x = (unsigned)f2bf(e0) | ((unsigned)f2bf(e1) << 16);
      w.y = (unsigned)f2bf(e2) | ((unsigned)f2bf(e3) << 16);
      *(u32x2*)(pt + lr * 128 + ((((f * 2 + (lg >> 1)) ^ (lr & 7))) << 4) + (lg & 1) * 8) = w;
    }
    csum += __shfl_xor(csum, 16);
    csum += __shfl_xor(csum, 32);
    lsum += csum;
#pragma unroll
    for (int ks = 0; ks < 2; ks++) {
      short8 pf = *(const short8*)(pt + lr * 128 + (((ks * 4 + lg) ^ (lr & 7)) << 4));
      {
        short8 vf = *(const short8*)(vt + ((long)(b * 256 + h * HD_ + 0 + lr)) * 512 + t0 + ks * 32 + lg * 8);
        o0 = __builtin_amdgcn_mfma_f32_16x16x32_bf16(pf, vf, o0, 0, 0, 0);
      }
      {
        short8 vf = *(const short8*)(vt + ((long)(b * 256 + h * HD_ + 16 + lr)) * 512 + t0 + ks * 32 + lg * 8);
        o1 = __builtin_amdgcn_mfma_f32_16x16x32_bf16(pf, vf, o1, 0, 0, 0);
      }
    }
  }
#pragma unroll
  for (int r = 0; r < 4; r++) {
    float li = 1.0f / __shfl(lsum, lg * 4 + r);
    long base = ((long)(b * L_ + q0 + lg * 4 + r)) * 512 + h * 64;
    float v0 = o0[r] * li, v1 = o1[r] * li;
    unsigned short h0 = f2bf(v0), h1 = f2bf(v1);
    ctxd[base + lr] = h0;
    ctxd[base + 32 + lr] = f2bf(v0 - bf2f(h0));
    ctxd[base + 16 + lr] = h1;
    ctxd[base + 48 + lr] = f2bf(v1 - bf2f(h1));
  }
}

extern "C" void kernel_launch(void* const* d_in, const int* in_sizes, int n_in, void* d_out, int out_size, void* d_ws,
                              size_t ws_size, hipStream_t stream) {
  (void)in_sizes; (void)n_in; (void)out_size; (void)ws_size;
  const float* qs_in = (const float*)d_in[0];
  const float* ctx_in = (const float*)d_in[1];
  const int* rind = (const int*)d_in[2];
  const float* ipw = (const float*)d_in[3];
  const float* ipb = (const float*)d_in[4];
  const float* opw = (const float*)d_in[5];
  const float* opb = (const float*)d_in[6];
  const float* c1w = (const float*)d_in[7];
  const float* c1b = (const float*)d_in[8];
  const float* g1 = (const float*)d_in[9];
  const float* b1 = (const float*)d_in[10];
  const float* mu1 = (const float*)d_in[11];
  const float* v1 = (const float*)d_in[12];
  const float* c2w = (const float*)d_in[13];
  const float* c2b = (const float*)d_in[14];
  const float* g2 = (const float*)d_in[15];
  const float* b2 = (const float*)d_in[16];
  const float* mu2 = (const float*)d_in[17];
  const float* v2 = (const float*)d_in[18];
  float* out = (float*)d_out;
  float* ws = (float*)d_ws;

  // ---- workspace layout (float offsets; 1MB = 262144 floats), peak ~74MB ----
  float* Qt = ws;                                             // [0,16)MB fp32; dead after Qsbuf gather
  unsigned short* ctxd = (unsigned short*)ws;                 // [0,16) duo, written by attn
  float* Kt = ws + 4194304;                                   // [16,32) fp32; dead after ksel gather
  float* X = ws + 4194304;                                    // [16,32) fp32, written by out-proj
  unsigned short* Qt_bf = (unsigned short*)(ws + 8388608);    // [32,40) bf16; dead after q-proj
  unsigned short* X_bf = (unsigned short*)(ws + 8388608);     // [32,40) bf16, written by out-proj
  float* Qsbuf = ws + 10485760;                               // [40,42)
  unsigned* md = (unsigned*)(ws + 11010048);                  // [42,42.06)
  unsigned* idxsel = (unsigned*)(ws + 11026432);              // 8KB
  unsigned short* ksel_bf = (unsigned short*)(ws + 11272192); // [43,44)
  unsigned short* q_bf = (unsigned short*)(ws + 11534336);    // [44,52)
  unsigned short* kv_k = (unsigned short*)(ws + 13631488);    // [52,53)
  unsigned short* v_t = (unsigned short*)(ws + 13893632);     // [53,54)
  unsigned short* H = (unsigned short*)(ws + 10485760);       // [40,72) bf16 hidden (overlays dead bufs)
  unsigned short* wq_bf = (unsigned short*)(ws + 18874368);   // [72,...)
  unsigned short* wkv_bf = (unsigned short*)(ws + 18907136);
  unsigned short* c1w_bf = (unsigned short*)(ws + 18972672);
  unsigned short* c2w_bf = (unsigned short*)(ws + 19103744);
  unsigned short* opw_d = (unsigned short*)(ws + 19234816);

  const float qscale = 0.17677669529663687f;  // 1/sqrt(32)

  // all weight converts + md init in one launch
  k_prep<<<480, 256, 0, stream>>>(ipw, opw, c1w, c2w, wq_bf, wkv_bf, c1w_bf, c2w_bf, opw_d, md);

  dim3 tb(32, 8);
  k_transpose<1><<<dim3(128, 8, 4), tb, 0, stream>>>(qs_in, Qt, Qt_bf);
  k_transpose<0><<<dim3(128, 8, 4), tb, 0, stream>>>(ctx_in, Kt, nullptr);
  k_gather_f32<<<512, 256, 0, stream>>>(Qt, rind, Qsbuf, TOPK_);
  k_dist<<<dim3(64, 4, 8), 256, 0, stream>>>(Kt, Qsbuf, md);
  k_sort<<<4, 1024, 0, stream>>>(md, idxsel);
  k_gather_bf<<<512, 256, 0, stream>>>(Kt, (const int*)idxsel, ksel_bf, TOPK_);

  // q projection -> q_bf (bias + 1/sqrt(HD) folded)
  k_gemm_s<64, 0><<<dim3(4, 128), 256, 0, stream>>>(Qt_bf, wq_bf, 256, 256, qscale, ipb, nullptr, nullptr, nullptr,
                                                    nullptr, nullptr, nullptr, q_bf, nullptr);
  // k/v projection -> kv_k + v_t
  k_gemm_s<64, 1><<<dim3(8, 16), 256, 0, stream>>>(ksel_bf, wkv_bf, 256, 512, 1.f, ipb + 256, nullptr, nullptr,
                                                   nullptr, nullptr, nullptr, nullptr, kv_k, v_t);
  // attention -> ctx duo
  k_attn_mfma<<<dim3(64, NH_, B_), 256, 0, stream>>>(q_bf, kv_k, v_t, ctxd);
  // out projection (duo x duo) -> X fp32 + X_bf
  k_gemm_d<<<dim3(4, 128), 256, 0, stream>>>(ctxd, opw_d, 256, opb, X, X_bf);
  // conv1 + bn + relu -> H bf16
  k_gemm_s<128, 3><<<dim3(8, 128), 256, 0, stream>>>(X_bf, c1w_bf, 256, 1024, 1.f, c1b, g1, b1, mu1, v1, nullptr,
                                                     nullptr, H, nullptr);
  // conv2 + bn + residual + transpose -> out
  k_gemm_s<64, 5><<<dim3(4, 128), 256, 0, stream>>>(H, c2w_bf, 1024, 256, 1.f, c2b, g2, b2, mu2, v2, X, out,
                                                    nullptr, nullptr);
}